// Round 2
// baseline (328.113 us; speedup 1.0000x reference)
//
#include <hip/hip_runtime.h>
#include <hip/hip_bf16.h>

using bf16 = __hip_bfloat16;
typedef __attribute__((ext_vector_type(8))) short bf16x8;
typedef __attribute__((ext_vector_type(4))) float f32x4;

#define C_2PI_8192 7.6699039394282072e-4f

// ---------------- K1: mask dtype detect + wt build (single block) ----------------
__global__ __launch_bounds__(1024) void k_detect_wt(const void* __restrict__ mask,
                                                    float* __restrict__ wt,
                                                    float* __restrict__ nobs) {
  __shared__ int cnt;
  int tid = threadIdx.x;
  if (tid == 0) cnt = 0;
  __syncthreads();
  const unsigned char* mb = (const unsigned char*)mask;
  int c = 0;
#pragma unroll
  for (int i = 0; i < 4; ++i) c += (mb[tid * 4 + i] != 0) ? 1 : 0;
  atomicAdd(&cnt, c);
  __syncthreads();
  bool bytemode = (cnt > 2048);
  const int* mi = (const int*)mask;
  for (int e = tid; e < 4096; e += 1024) {
    bool on = bytemode ? (mb[e] != 0) : (mi[e] != 0);
    wt[e] = on ? 1.0f : 0.0f;
  }
  __syncthreads();
  if (tid < 4) {
    float s = 0.f;
    for (int t = 0; t < 1024; ++t) s += wt[tid * 1024 + t];
    nobs[tid] = s;
  }
}

// ---------------- K2: A1[f'][t] basis (t contiguous), bf16
__global__ void k_build_A1(bf16* __restrict__ A1) {
  int idx = blockIdx.x * blockDim.x + threadIdx.x;  // 8192*1024
  int f = idx >> 10, t = idx & 1023;
  int fm = (f & 4095) + 1;
  int ph = (fm * (t + 1)) & 8191;
  float x = ph * C_2PI_8192;
  float v = (f < 4096) ? __sinf(x) : __cosf(x);
  A1[idx] = __float2bfloat16(v);
}

// ---------------- K3: B2[t][k] basis (k contiguous), bf16
__global__ void k_build_B2(bf16* __restrict__ B2) {
  int idx = blockIdx.x * blockDim.x + threadIdx.x;  // 1024*8192
  int t = idx >> 13, k = idx & 8191;
  int km = (k & 4095) + 1;
  int ph = (km * (t + 1)) & 8191;
  float x = ph * C_2PI_8192;
  float v = (k < 4096) ? __sinf(x) : __cosf(x);
  B2[idx] = __float2bfloat16(v);
}

// ---------------- K4: dm[bc][t] = bf16(data * wt)
__global__ void k_build_dm(const float* __restrict__ data, const float* __restrict__ wt,
                           bf16* __restrict__ dm) {
  int idx = blockIdx.x * blockDim.x + threadIdx.x;  // 2048*1024
  int t = idx & 1023;
  int b = idx >> 19;
  dm[idx] = __float2bfloat16(data[idx] * wt[(b << 10) + t]);
}

// ---------------- K5: per-(b,f) tau stats -> {cos th, sin th, 1/den_s, 1/den_c}
__global__ __launch_bounds__(256) void k_tau(const float* __restrict__ wt,
                                             const float* __restrict__ nobs,
                                             float4* __restrict__ scal) {
  int gw = blockIdx.x * 4 + (threadIdx.x >> 6);  // one wave per (b,f)
  int lane = threadIdx.x & 63;
  int b = gw >> 12, f = gw & 4095;
  float num = 0.f, den = 0.f;
  int f2 = 2 * (f + 1);
  for (int t = lane; t < 1024; t += 64) {
    float w = wt[(b << 10) + t];
    int ph = (f2 * (t + 1)) & 8191;
    float x = ph * C_2PI_8192;
    num += w * __sinf(x);
    den += w * __cosf(x);
  }
#pragma unroll
  for (int m = 32; m; m >>= 1) {
    num += __shfl_xor(num, m, 64);
    den += __shfl_xor(den, m, 64);
  }
  if (lane == 0) {
    if (f == 4095) {
      // ang = pi: sin basis degenerates (handled by the f32-replica fixup path).
      // ids = 0 kills the sin spectrum here -> P=0 in k_pq.
      float nb = nobs[b];
      scal[gw] = make_float4(1.f, 0.f, 0.f, 1.f / nb);
    } else {
      float th = 0.5f * atan2f(num, den);   // = ang * tau
      float c = cosf(th), s = sinf(th);
      float nb = nobs[b];
      float WSS = 0.5f * (nb - den);        // sum wt sin^2(arg)
      float WCC = 0.5f * (nb + den);        // sum wt cos^2(arg)
      float WSC = 0.5f * num;               // sum wt sin cos
      float den_s = c * c * WSS - 2.f * c * s * WSC + s * s * WCC;
      float den_c = c * c * WCC + 2.f * c * s * WSC + s * s * WSS;
      scal[gw] = make_float4(c, s, 1.f / den_s, 1.f / den_c);
    }
  }
}

// ---------------- f=4095 fixup (a): replicate reference f32 arithmetic per b
// delta[b][t] = sin(fl32(ang*t) - fl32(ang*tau)); invA[b] = 1/sum(wt*delta^2)
__global__ __launch_bounds__(256) void k_f4095a(const float* __restrict__ wt,
                                                float* __restrict__ delta,
                                                float* __restrict__ invA) {
  const float W = (float)(6.283185307179586 / 8192.0);  // fl32 of 2pi*freqstep
  const float ang = W * 4096.0f;                        // exact pow2 scale
  int b = threadIdx.x >> 6;
  int lane = threadIdx.x & 63;
  const float* wp = wt + (b << 10);
  float num = 0.f, den = 0.f;
  for (int t = lane; t < 1024; t += 64) {
    float tf = (float)(t + 1);
    float arg = ang * tf;                 // f32, matches ref rounding
    float w = wp[t];
    num += w * sinf(2.0f * arg);
    den += w * cosf(2.0f * arg);
  }
#pragma unroll
  for (int m = 32; m; m >>= 1) {
    num += __shfl_xor(num, m, 64);
    den += __shfl_xor(den, m, 64);
  }
  // replicate: tau = atan2(num,den)/(2*ang); P = ang*tau  (all f32)
  float tau = atan2f(num, den) / (2.0f * ang);
  float P = ang * tau;
  float dss = 0.f;
  for (int t = lane; t < 1024; t += 64) {
    float tf = (float)(t + 1);
    float arg = ang * tf;
    float d = sinf(arg - P);              // f32 subtract then accurate sin
    delta[(b << 10) + t] = d;
    dss += wp[t] * d * d;
  }
#pragma unroll
  for (int m = 32; m; m >>= 1) dss += __shfl_xor(dss, m, 64);
  if (lane == 0) invA[b] = 1.f / dss;
}

// ---------------- f=4095 fixup (b): ss[bc] = invA[b] * sum_t wt*delta*data
__global__ __launch_bounds__(256) void k_f4095b(const float* __restrict__ data,
                                                const float* __restrict__ wt,
                                                const float* __restrict__ delta,
                                                const float* __restrict__ invA,
                                                float* __restrict__ ss4095) {
  int bc = blockIdx.x * 4 + (threadIdx.x >> 6);
  int lane = threadIdx.x & 63;
  int b = bc >> 9;
  const float* dp = data + (size_t)bc * 1024;
  const float* wp = wt + (b << 10);
  const float* del = delta + (b << 10);
  float s = 0.f;
  for (int t = lane; t < 1024; t += 64) s += wp[t] * del[t] * dp[t];
#pragma unroll
  for (int m = 32; m; m >>= 1) s += __shfl_xor(s, m, 64);
  if (lane == 0) ss4095[bc] = s * invA[b];
}

// ---------------- f=4095 fixup (c): recon += delta[b][t] * ss[bc]
__global__ void k_f4095c(float* __restrict__ out, const float* __restrict__ delta,
                         const float* __restrict__ ss4095) {
  int idx = blockIdx.x * blockDim.x + threadIdx.x;  // 2M
  int t = idx & 1023, bc = idx >> 10, b = bc >> 9;
  out[idx] += delta[(b << 10) + t] * ss4095[bc];
}

// ---------------- GEMM (NT): C[m][n] = sum_k A[m][k]*B[n][k]; 128x128 tile, BK=32
__global__ __launch_bounds__(256) void k_gemm_nt(const bf16* __restrict__ A,
                                                 const bf16* __restrict__ B,
                                                 float* __restrict__ C,
                                                 int N, int K, int mtiles) {
  __shared__ bf16 As[128 * 32];
  __shared__ bf16 Bs[128 * 32];
  int bid = blockIdx.x;
  int mt = bid % mtiles, nt = bid / mtiles;
  int tid = threadIdx.x;
  int lane = tid & 63, wid = tid >> 6;
  int wm = (wid >> 1) << 6, wn = (wid & 1) << 6;
  int fr = lane & 15, kh = lane >> 4;
  size_t m0 = (size_t)mt * 128, n0 = (size_t)nt * 128;

  int c1 = tid, c2 = tid + 256;
  const bf16* pa1 = A + (m0 + (c1 >> 2)) * (size_t)K + (c1 & 3) * 8;
  const bf16* pa2 = A + (m0 + (c2 >> 2)) * (size_t)K + (c2 & 3) * 8;
  const bf16* pb1 = B + (n0 + (c1 >> 2)) * (size_t)K + (c1 & 3) * 8;
  const bf16* pb2 = B + (n0 + (c2 >> 2)) * (size_t)K + (c2 & 3) * 8;
  char* lA1 = (char*)As + (wid << 10);
  char* lA2 = (char*)As + 4096 + (wid << 10);
  char* lB1 = (char*)Bs + (wid << 10);
  char* lB2 = (char*)Bs + 4096 + (wid << 10);

  f32x4 acc[4][4] = {};

  int ksteps = K >> 5;
  for (int kt = 0; kt < ksteps; ++kt) {
    __builtin_amdgcn_global_load_lds((const __attribute__((address_space(1))) void*)pa1,
                                     (__attribute__((address_space(3))) void*)lA1, 16, 0, 0);
    __builtin_amdgcn_global_load_lds((const __attribute__((address_space(1))) void*)pa2,
                                     (__attribute__((address_space(3))) void*)lA2, 16, 0, 0);
    __builtin_amdgcn_global_load_lds((const __attribute__((address_space(1))) void*)pb1,
                                     (__attribute__((address_space(3))) void*)lB1, 16, 0, 0);
    __builtin_amdgcn_global_load_lds((const __attribute__((address_space(1))) void*)pb2,
                                     (__attribute__((address_space(3))) void*)lB2, 16, 0, 0);
    pa1 += 32; pa2 += 32; pb1 += 32; pb2 += 32;
    __syncthreads();
    bf16x8 a[4], b[4];
#pragma unroll
    for (int i = 0; i < 4; ++i)
      a[i] = *(const bf16x8*)&As[(wm + i * 16 + fr) * 32 + kh * 8];
#pragma unroll
    for (int j = 0; j < 4; ++j)
      b[j] = *(const bf16x8*)&Bs[(wn + j * 16 + fr) * 32 + kh * 8];
#pragma unroll
    for (int i = 0; i < 4; ++i)
#pragma unroll
      for (int j = 0; j < 4; ++j)
        acc[i][j] = __builtin_amdgcn_mfma_f32_16x16x32_bf16(a[i], b[j], acc[i][j], 0, 0, 0);
    __syncthreads();
  }
#pragma unroll
  for (int i = 0; i < 4; ++i) {
#pragma unroll
    for (int q = 0; q < 4; ++q) {
      size_t row = m0 + wm + i * 16 + kh * 4 + q;
      float* cp = C + row * (size_t)N + n0 + wn + fr;
#pragma unroll
      for (int j = 0; j < 4; ++j) cp[j * 16] = acc[i][j][q];
    }
  }
}

// ---------------- K7: spectra -> P,Q with transpose (f,bc)->(bc,f')
__global__ __launch_bounds__(256) void k_pq(const float* __restrict__ G,
                                            const float4* __restrict__ scal,
                                            bf16* __restrict__ PQ) {
  __shared__ float lS[64][65];
  __shared__ float lC[64][65];
  int bc0 = blockIdx.x << 6;
  int f0 = blockIdx.y << 6;
  int tid = threadIdx.x;
  int colr = tid & 63, rowg = tid >> 6;
#pragma unroll
  for (int p = 0; p < 16; ++p) {
    int row = p * 4 + rowg;
    lS[row][colr] = G[(size_t)(f0 + row) * 2048 + bc0 + colr];
    lC[row][colr] = G[(size_t)(4096 + f0 + row) * 2048 + bc0 + colr];
  }
  __syncthreads();
  int fl = tid & 63;
  int f = f0 + fl;
  int b = bc0 >> 9;
  float4 sc = scal[(b << 12) + f];
  float c = sc.x, s = sc.y, ids = sc.z, idc = sc.w;
#pragma unroll
  for (int p = 0; p < 16; ++p) {
    int bcl = p * 4 + rowg;
    float GS = lS[fl][bcl];
    float GC = lC[fl][bcl];
    float ss = (c * GS - s * GC) * ids;  // sin spectrum (0 at f=4095: ids=0)
    float cs = (c * GC + s * GS) * idc;  // cos spectrum
    float P = c * ss + s * cs;
    float Q = c * cs - s * ss;
    size_t base = (size_t)(bc0 + bcl) << 13;
    PQ[base + f] = __float2bfloat16(P);
    PQ[base + 4096 + f] = __float2bfloat16(Q);
  }
}

// ---------------- K9: per-(b,c) weighted std ratio
__global__ __launch_bounds__(256) void k_stats(const float* __restrict__ recon,
                                               const float* __restrict__ data,
                                               const float* __restrict__ wt,
                                               const float* __restrict__ nobs,
                                               float* __restrict__ invnf) {
  int bc = blockIdx.x;
  int b = bc >> 9;
  int tid = threadIdx.x;
  float sr = 0, sr2 = 0, sd = 0, sd2 = 0;
  const float* rp = recon + (size_t)bc * 1024;
  const float* dp = data + (size_t)bc * 1024;
  const float* wp = wt + (b << 10);
  for (int t = tid; t < 1024; t += 256) {
    float w = wp[t], r = rp[t], d = dp[t];
    sr += w * r; sr2 += w * r * r;
    sd += w * d; sd2 += w * d * d;
  }
#pragma unroll
  for (int m = 32; m; m >>= 1) {
    sr += __shfl_xor(sr, m, 64);
    sr2 += __shfl_xor(sr2, m, 64);
    sd += __shfl_xor(sd, m, 64);
    sd2 += __shfl_xor(sd2, m, 64);
  }
  __shared__ float red[4][4];
  int wid = tid >> 6, lane = tid & 63;
  if (lane == 0) { red[wid][0] = sr; red[wid][1] = sr2; red[wid][2] = sd; red[wid][3] = sd2; }
  __syncthreads();
  if (tid == 0) {
    float a = 0, b2 = 0, cq = 0, d2 = 0;
    for (int w = 0; w < 4; ++w) { a += red[w][0]; b2 += red[w][1]; cq += red[w][2]; d2 += red[w][3]; }
    float n = nobs[b];
    float mr = a / n, md = cq / n;
    float vr = (b2 - n * mr * mr) / (n - 1.f);
    float vd = (d2 - n * md * md) / (n - 1.f);
    invnf[bc] = sqrtf(vd / vr);
  }
}

// ---------------- K10: out = mask ? data : recon * invnf
__global__ void k_final(float* __restrict__ out, const float* __restrict__ data,
                        const float* __restrict__ wt, const float* __restrict__ invnf) {
  int idx = blockIdx.x * blockDim.x + threadIdx.x;  // 2M
  int t = idx & 1023, bc = idx >> 10, b = bc >> 9;
  float w = wt[(b << 10) + t];
  float r = out[idx];
  out[idx] = (w != 0.f) ? data[idx] : r * invnf[bc];
}

extern "C" void kernel_launch(void* const* d_in, const int* in_sizes, int n_in,
                              void* d_out, int out_size, void* d_ws, size_t ws_size,
                              hipStream_t stream) {
  const float* data = (const float*)d_in[0];
  const void* mask = d_in[1];
  float* out = (float*)d_out;
  char* ws = (char*)d_ws;

  float* wt = (float*)(ws);                         // 16 KB
  float* nobs = (float*)(ws + 16384);               // 16 B
  float4* scal = (float4*)(ws + 32768);             // 256 KB
  float* invnf = (float*)(ws + 294912);             // 8 KB
  float* delta = (float*)(ws + 303104);             // 16 KB (f=4095 basis per b)
  float* ss4095 = (float*)(ws + 319488);            // 8 KB
  float* invA = (float*)(ws + 327680);              // 16 B
  const size_t MB = 1ull << 20;
  bf16* A1 = (bf16*)(ws + 1 * MB);    // 8192x1024 bf16 = 16 MB
  bf16* B2 = (bf16*)(ws + 17 * MB);   // 1024x8192 bf16 = 16 MB
  bf16* dm = (bf16*)(ws + 33 * MB);   // 2048x1024 bf16 = 4 MB
  float* G = (float*)(ws + 37 * MB);  // 8192x2048 f32  = 64 MB
  bf16* PQ = (bf16*)(ws + 101 * MB);  // 2048x8192 bf16 = 32 MB

  k_detect_wt<<<1, 1024, 0, stream>>>(mask, wt, nobs);
  k_build_A1<<<(8192 * 1024) / 256, 256, 0, stream>>>(A1);
  k_build_B2<<<(1024 * 8192) / 256, 256, 0, stream>>>(B2);
  k_build_dm<<<(2048 * 1024) / 256, 256, 0, stream>>>(data, wt, dm);
  k_tau<<<4096, 256, 0, stream>>>(wt, nobs, scal);
  k_f4095a<<<1, 256, 0, stream>>>(wt, delta, invA);
  k_f4095b<<<512, 256, 0, stream>>>(data, wt, delta, invA, ss4095);
  // GEMM1: G[f'][bc] = sum_t A1[f'][t] * dm[bc][t]   (M=8192,N=2048,K=1024)
  k_gemm_nt<<<1024, 256, 0, stream>>>(A1, dm, G, 2048, 1024, 64);
  dim3 pqgrid(32, 64);
  k_pq<<<pqgrid, 256, 0, stream>>>(G, scal, PQ);
  // GEMM2: recon[bc][t] = sum_k PQ[bc][k] * B2[t][k]  (M=2048,N=1024,K=8192)
  k_gemm_nt<<<128, 256, 0, stream>>>(PQ, B2, out, 1024, 8192, 16);
  k_f4095c<<<(2048 * 1024) / 256, 256, 0, stream>>>(out, delta, ss4095);
  k_stats<<<2048, 256, 0, stream>>>(out, data, wt, nobs, invnf);
  k_final<<<(2048 * 1024) / 256, 256, 0, stream>>>(out, data, wt, invnf);
}

// Round 3
// 208.214 us; speedup vs baseline: 1.5758x; 1.5758x over previous
//
#include <hip/hip_runtime.h>
#include <hip/hip_bf16.h>

using bf16 = __hip_bfloat16;
typedef __attribute__((ext_vector_type(8))) short bf16x8;
typedef __attribute__((ext_vector_type(4))) short short4v;
typedef __attribute__((ext_vector_type(4))) float f32x4;

#define C_2PI_8192 7.6699039394282072e-4f

static __device__ __forceinline__ short bf16bits(float v) {
  bf16 h = __float2bfloat16(v);
  return *reinterpret_cast<short*>(&h);
}

// ---------------- K1: mask dtype detect + wt build (single block) ----------------
__global__ __launch_bounds__(1024) void k_detect_wt(const void* __restrict__ mask,
                                                    float* __restrict__ wt,
                                                    float* __restrict__ nobs) {
  __shared__ int cnt;
  int tid = threadIdx.x;
  if (tid == 0) cnt = 0;
  __syncthreads();
  const unsigned char* mb = (const unsigned char*)mask;
  int c = 0;
#pragma unroll
  for (int i = 0; i < 4; ++i) c += (mb[tid * 4 + i] != 0) ? 1 : 0;
  atomicAdd(&cnt, c);
  __syncthreads();
  bool bytemode = (cnt > 2048);
  const int* mi = (const int*)mask;
  for (int e = tid; e < 4096; e += 1024) {
    bool on = bytemode ? (mb[e] != 0) : (mi[e] != 0);
    wt[e] = on ? 1.0f : 0.0f;
  }
  __syncthreads();
  if (tid < 4) {
    float s = 0.f;
    for (int t = 0; t < 1024; ++t) s += wt[tid * 1024 + t];
    nobs[tid] = s;
  }
}

// ---------------- K2: A1[f'][t] basis (t contiguous), bf16, 8 t per thread
__global__ void k_build_A1(bf16* __restrict__ A1) {
  int idx = blockIdx.x * blockDim.x + threadIdx.x;  // 8192*128
  int f = idx >> 7, t8 = (idx & 127) << 3;
  int fm = (f & 4095) + 1;
  bool is_sin = (f < 4096);
  int ph = (fm * (t8 + 1)) & 8191;
  short4v lo, hi;
#pragma unroll
  for (int j = 0; j < 8; ++j) {
    float x = ph * C_2PI_8192;
    float v = is_sin ? __sinf(x) : __cosf(x);
    if (j < 4) lo[j] = bf16bits(v); else hi[j - 4] = bf16bits(v);
    ph = (ph + fm) & 8191;
  }
  short* dst = (short*)&A1[((size_t)f << 10) + t8];
  *(short4v*)dst = lo;
  *(short4v*)(dst + 4) = hi;
}

// ---------------- K3: B2[t][k] basis (k contiguous), bf16, 8 k per thread
__global__ void k_build_B2(bf16* __restrict__ B2) {
  int idx = blockIdx.x * blockDim.x + threadIdx.x;  // 1024*1024
  int t = idx >> 10, k8 = (idx & 1023) << 3;
  int tp = t + 1;
  bool is_sin = (k8 < 4096);
  int km = (k8 & 4095) + 1;
  int ph = (km * tp) & 8191;
  short4v lo, hi;
#pragma unroll
  for (int j = 0; j < 8; ++j) {
    float x = ph * C_2PI_8192;
    float v = is_sin ? __sinf(x) : __cosf(x);
    if (j < 4) lo[j] = bf16bits(v); else hi[j - 4] = bf16bits(v);
    ph = (ph + tp) & 8191;
  }
  short* dst = (short*)&B2[((size_t)t << 13) + k8];
  *(short4v*)dst = lo;
  *(short4v*)(dst + 4) = hi;
}

// ---------------- K4: dm[bc][t] = bf16(data * wt)
__global__ void k_build_dm(const float* __restrict__ data, const float* __restrict__ wt,
                           bf16* __restrict__ dm) {
  int idx = blockIdx.x * blockDim.x + threadIdx.x;  // 2048*1024
  int t = idx & 1023;
  int b = idx >> 19;
  dm[idx] = __float2bfloat16(data[idx] * wt[(b << 10) + t]);
}

// ---------------- K5: per-(b,f) tau stats -> {cos th, sin th, 1/den_s, 1/den_c}
__global__ __launch_bounds__(256) void k_tau(const float* __restrict__ wt,
                                             const float* __restrict__ nobs,
                                             float4* __restrict__ scal) {
  int gw = blockIdx.x * 4 + (threadIdx.x >> 6);  // one wave per (b,f)
  int lane = threadIdx.x & 63;
  int b = gw >> 12, f = gw & 4095;
  float num = 0.f, den = 0.f;
  int f2 = 2 * (f + 1);
  for (int t = lane; t < 1024; t += 64) {
    float w = wt[(b << 10) + t];
    int ph = (f2 * (t + 1)) & 8191;
    float x = ph * C_2PI_8192;
    num += w * __sinf(x);
    den += w * __cosf(x);
  }
#pragma unroll
  for (int m = 32; m; m >>= 1) {
    num += __shfl_xor(num, m, 64);
    den += __shfl_xor(den, m, 64);
  }
  if (lane == 0) {
    if (f == 4095) {
      // ang = pi: sin basis degenerate; handled by f32-replica fixup path.
      float nb = nobs[b];
      scal[gw] = make_float4(1.f, 0.f, 0.f, 1.f / nb);
    } else {
      float th = 0.5f * atan2f(num, den);   // = ang * tau
      float c = cosf(th), s = sinf(th);
      float nb = nobs[b];
      float WSS = 0.5f * (nb - den);
      float WCC = 0.5f * (nb + den);
      float WSC = 0.5f * num;
      float den_s = c * c * WSS - 2.f * c * s * WSC + s * s * WCC;
      float den_c = c * c * WCC + 2.f * c * s * WSC + s * s * WSS;
      scal[gw] = make_float4(c, s, 1.f / den_s, 1.f / den_c);
    }
  }
}

// ---------------- f=4095 fixup (a): replicate reference f32 arithmetic per b
__global__ __launch_bounds__(256) void k_f4095a(const float* __restrict__ wt,
                                                float* __restrict__ delta,
                                                float* __restrict__ invA) {
  const float W = (float)(6.283185307179586 / 8192.0);
  const float ang = W * 4096.0f;
  int b = threadIdx.x >> 6;
  int lane = threadIdx.x & 63;
  const float* wp = wt + (b << 10);
  float num = 0.f, den = 0.f;
  for (int t = lane; t < 1024; t += 64) {
    float tf = (float)(t + 1);
    float arg = ang * tf;
    float w = wp[t];
    num += w * sinf(2.0f * arg);
    den += w * cosf(2.0f * arg);
  }
#pragma unroll
  for (int m = 32; m; m >>= 1) {
    num += __shfl_xor(num, m, 64);
    den += __shfl_xor(den, m, 64);
  }
  float tau = atan2f(num, den) / (2.0f * ang);
  float P = ang * tau;
  float dss = 0.f;
  for (int t = lane; t < 1024; t += 64) {
    float tf = (float)(t + 1);
    float arg = ang * tf;
    float d = sinf(arg - P);
    delta[(b << 10) + t] = d;
    dss += wp[t] * d * d;
  }
#pragma unroll
  for (int m = 32; m; m >>= 1) dss += __shfl_xor(dss, m, 64);
  if (lane == 0) invA[b] = 1.f / dss;
}

// ---------------- f=4095 fixup (b): ss[bc] = invA[b] * sum_t wt*delta*data
__global__ __launch_bounds__(256) void k_f4095b(const float* __restrict__ data,
                                                const float* __restrict__ wt,
                                                const float* __restrict__ delta,
                                                const float* __restrict__ invA,
                                                float* __restrict__ ss4095) {
  int bc = blockIdx.x * 4 + (threadIdx.x >> 6);
  int lane = threadIdx.x & 63;
  int b = bc >> 9;
  const float* dp = data + (size_t)bc * 1024;
  const float* wp = wt + (b << 10);
  const float* del = delta + (b << 10);
  float s = 0.f;
  for (int t = lane; t < 1024; t += 64) s += wp[t] * del[t] * dp[t];
#pragma unroll
  for (int m = 32; m; m >>= 1) s += __shfl_xor(s, m, 64);
  if (lane == 0) ss4095[bc] = s * invA[b];
}

// ---------------- GEMM (NT) with optional split-K: C[m][n] = sum_k A[m][k]*B[n][k]
// 128x128 tile, BK=32, mtiles hardcoded 16. LDS XOR-swizzled (st-style):
// LDS[row][col16] holds global chunk col16 ^ ((row>>1)&3)  -> 2-way banks on read.
__global__ __launch_bounds__(256) void k_gemm_nt(const bf16* __restrict__ A,
                                                 const bf16* __restrict__ B,
                                                 float* __restrict__ C,
                                                 int lda, int ldb, int ldc,
                                                 int tiles_per_slice, int k0_step,
                                                 int cstride) {
  __shared__ bf16 As[128 * 32];
  __shared__ bf16 Bs[128 * 32];
  int bid = blockIdx.x;
  int slice = bid / tiles_per_slice;
  int tl = bid % tiles_per_slice;
  int mt = tl & 15, nt = tl >> 4;
  A += (size_t)slice * k0_step;
  B += (size_t)slice * k0_step;
  C += (size_t)slice * cstride;
  int tid = threadIdx.x;
  int lane = tid & 63, wid = tid >> 6;
  int wm = (wid >> 1) << 6, wn = (wid & 1) << 6;
  int fr = lane & 15, kh = lane >> 4;
  size_t m0 = (size_t)mt * 128, n0 = (size_t)nt * 128;

  // staging chunk c in [0,512): row=c>>2, col16=c&3, source col pre-swizzled
  int c1 = tid, c2 = tid + 256;
  int r1 = c1 >> 2, r2 = c2 >> 2;
  int sc1 = ((c1 & 3) ^ ((r1 >> 1) & 3)) << 3;  // element offset
  int sc2 = ((c2 & 3) ^ ((r2 >> 1) & 3)) << 3;
  const bf16* pa1 = A + (m0 + r1) * (size_t)lda + sc1;
  const bf16* pa2 = A + (m0 + r2) * (size_t)lda + sc2;
  const bf16* pb1 = B + (n0 + r1) * (size_t)ldb + sc1;
  const bf16* pb2 = B + (n0 + r2) * (size_t)ldb + sc2;
  char* lA1 = (char*)As + (wid << 10);
  char* lA2 = (char*)As + 4096 + (wid << 10);
  char* lB1 = (char*)Bs + (wid << 10);
  char* lB2 = (char*)Bs + 4096 + (wid << 10);

  f32x4 acc[4][4] = {};
  int swr = (fr >> 1) & 3;  // read-side swizzle (row bits from fr)

  for (int kt = 0; kt < 32; ++kt) {
    __builtin_amdgcn_global_load_lds((const __attribute__((address_space(1))) void*)pa1,
                                     (__attribute__((address_space(3))) void*)lA1, 16, 0, 0);
    __builtin_amdgcn_global_load_lds((const __attribute__((address_space(1))) void*)pa2,
                                     (__attribute__((address_space(3))) void*)lA2, 16, 0, 0);
    __builtin_amdgcn_global_load_lds((const __attribute__((address_space(1))) void*)pb1,
                                     (__attribute__((address_space(3))) void*)lB1, 16, 0, 0);
    __builtin_amdgcn_global_load_lds((const __attribute__((address_space(1))) void*)pb2,
                                     (__attribute__((address_space(3))) void*)lB2, 16, 0, 0);
    pa1 += 32; pa2 += 32; pb1 += 32; pb2 += 32;
    __syncthreads();
    bf16x8 a[4], b[4];
#pragma unroll
    for (int i = 0; i < 4; ++i)
      a[i] = *(const bf16x8*)&As[(wm + i * 16 + fr) * 32 + ((kh ^ swr) << 3)];
#pragma unroll
    for (int j = 0; j < 4; ++j)
      b[j] = *(const bf16x8*)&Bs[(wn + j * 16 + fr) * 32 + ((kh ^ swr) << 3)];
#pragma unroll
    for (int i = 0; i < 4; ++i)
#pragma unroll
      for (int j = 0; j < 4; ++j)
        acc[i][j] = __builtin_amdgcn_mfma_f32_16x16x32_bf16(a[i], b[j], acc[i][j], 0, 0, 0);
    __syncthreads();
  }
  // C/D layout: col=lane&15, row=(lane>>4)*4+q
#pragma unroll
  for (int i = 0; i < 4; ++i) {
#pragma unroll
    for (int q = 0; q < 4; ++q) {
      size_t row = m0 + wm + i * 16 + kh * 4 + q;
      float* cp = C + row * (size_t)ldc + n0 + wn + fr;
#pragma unroll
      for (int j = 0; j < 4; ++j) cp[j * 16] = acc[i][j][q];
    }
  }
}

// ---------------- K7: spectra -> P,Q (elementwise; G is [bc][f'])
__global__ void k_pq(const float* __restrict__ G, const float4* __restrict__ scal,
                     bf16* __restrict__ PQ) {
  int idx = blockIdx.x * blockDim.x + threadIdx.x;  // 2M threads, 4 f each
  int f4 = (idx & 1023) << 2;
  int bc = idx >> 10;
  int b = bc >> 9;
  size_t gbase = ((size_t)bc << 13);
  float4 GS = *(const float4*)(G + gbase + f4);
  float4 GC = *(const float4*)(G + gbase + 4096 + f4);
  const float* gs = (const float*)&GS;
  const float* gc = (const float*)&GC;
  short4v P, Q;
#pragma unroll
  for (int j = 0; j < 4; ++j) {
    float4 sc = scal[(b << 12) + f4 + j];
    float c = sc.x, s = sc.y, ids = sc.z, idc = sc.w;
    float ss = (c * gs[j] - s * gc[j]) * ids;
    float cs = (c * gc[j] + s * gs[j]) * idc;
    P[j] = bf16bits(c * ss + s * cs);
    Q[j] = bf16bits(c * cs - s * ss);
  }
  *(short4v*)((short*)PQ + gbase + f4) = P;
  *(short4v*)((short*)PQ + gbase + 4096 + f4) = Q;
}

// ---------------- K8: out = sum of 8 split-K partials + f4095 correction
__global__ void k_reduce8(const float* __restrict__ Ps, float* __restrict__ out,
                          const float* __restrict__ delta,
                          const float* __restrict__ ss4095) {
  int idx = blockIdx.x * blockDim.x + threadIdx.x;  // 512K threads, float4 each
  size_t base = (size_t)idx << 2;
  float4 acc = make_float4(0.f, 0.f, 0.f, 0.f);
#pragma unroll
  for (int s = 0; s < 8; ++s) {
    float4 v = *(const float4*)(Ps + (size_t)s * 2097152 + base);
    acc.x += v.x; acc.y += v.y; acc.z += v.z; acc.w += v.w;
  }
  int bc = (int)(base >> 10);
  int b = bc >> 9;
  int t0 = (int)(base & 1023);
  float ssv = ss4095[bc];
  const float* del = delta + (b << 10) + t0;
  float4 r = make_float4(acc.x + del[0] * ssv, acc.y + del[1] * ssv,
                         acc.z + del[2] * ssv, acc.w + del[3] * ssv);
  *(float4*)(out + base) = r;
}

// ---------------- K9: per-(b,c) weighted std ratio
__global__ __launch_bounds__(256) void k_stats(const float* __restrict__ recon,
                                               const float* __restrict__ data,
                                               const float* __restrict__ wt,
                                               const float* __restrict__ nobs,
                                               float* __restrict__ invnf) {
  int bc = blockIdx.x;
  int b = bc >> 9;
  int tid = threadIdx.x;
  float sr = 0, sr2 = 0, sd = 0, sd2 = 0;
  const float* rp = recon + (size_t)bc * 1024;
  const float* dp = data + (size_t)bc * 1024;
  const float* wp = wt + (b << 10);
  for (int t = tid; t < 1024; t += 256) {
    float w = wp[t], r = rp[t], d = dp[t];
    sr += w * r; sr2 += w * r * r;
    sd += w * d; sd2 += w * d * d;
  }
#pragma unroll
  for (int m = 32; m; m >>= 1) {
    sr += __shfl_xor(sr, m, 64);
    sr2 += __shfl_xor(sr2, m, 64);
    sd += __shfl_xor(sd, m, 64);
    sd2 += __shfl_xor(sd2, m, 64);
  }
  __shared__ float red[4][4];
  int wid = tid >> 6, lane = tid & 63;
  if (lane == 0) { red[wid][0] = sr; red[wid][1] = sr2; red[wid][2] = sd; red[wid][3] = sd2; }
  __syncthreads();
  if (tid == 0) {
    float a = 0, b2 = 0, cq = 0, d2 = 0;
    for (int w = 0; w < 4; ++w) { a += red[w][0]; b2 += red[w][1]; cq += red[w][2]; d2 += red[w][3]; }
    float n = nobs[b];
    float mr = a / n, md = cq / n;
    float vr = (b2 - n * mr * mr) / (n - 1.f);
    float vd = (d2 - n * md * md) / (n - 1.f);
    invnf[bc] = sqrtf(vd / vr);
  }
}

// ---------------- K10: out = mask ? data : recon * invnf
__global__ void k_final(float* __restrict__ out, const float* __restrict__ data,
                        const float* __restrict__ wt, const float* __restrict__ invnf) {
  int idx = blockIdx.x * blockDim.x + threadIdx.x;  // 2M
  int t = idx & 1023, bc = idx >> 10, b = bc >> 9;
  float w = wt[(b << 10) + t];
  float r = out[idx];
  out[idx] = (w != 0.f) ? data[idx] : r * invnf[bc];
}

extern "C" void kernel_launch(void* const* d_in, const int* in_sizes, int n_in,
                              void* d_out, int out_size, void* d_ws, size_t ws_size,
                              hipStream_t stream) {
  const float* data = (const float*)d_in[0];
  const void* mask = d_in[1];
  float* out = (float*)d_out;
  char* ws = (char*)d_ws;

  float* wt = (float*)(ws);                         // 16 KB
  float* nobs = (float*)(ws + 16384);               // 16 B
  float4* scal = (float4*)(ws + 32768);             // 256 KB
  float* invnf = (float*)(ws + 294912);             // 8 KB
  float* delta = (float*)(ws + 303104);             // 16 KB
  float* ss4095 = (float*)(ws + 319488);            // 8 KB
  float* invA = (float*)(ws + 327680);              // 16 B
  const size_t MB = 1ull << 20;
  bf16* A1 = (bf16*)(ws + 1 * MB);    // 8192x1024 bf16 = 16 MB  [f'][t]
  bf16* B2 = (bf16*)(ws + 17 * MB);   // 1024x8192 bf16 = 16 MB  [t][k']
  bf16* dm = (bf16*)(ws + 33 * MB);   // 2048x1024 bf16 = 4 MB
  float* G = (float*)(ws + 37 * MB);  // 64 MB: GEMM1 out [bc][f'], then split-K partials
  bf16* PQ = (bf16*)(ws + 101 * MB);  // 2048x8192 bf16 = 32 MB  [bc][k']

  k_detect_wt<<<1, 1024, 0, stream>>>(mask, wt, nobs);
  k_build_A1<<<(8192 * 128) / 256, 256, 0, stream>>>(A1);
  k_build_B2<<<(1024 * 1024) / 256, 256, 0, stream>>>(B2);
  k_build_dm<<<(2048 * 1024) / 256, 256, 0, stream>>>(data, wt, dm);
  k_tau<<<4096, 256, 0, stream>>>(wt, nobs, scal);
  k_f4095a<<<1, 256, 0, stream>>>(wt, delta, invA);
  k_f4095b<<<512, 256, 0, stream>>>(data, wt, delta, invA, ss4095);
  // GEMM1: G[bc][f'] = sum_t dm[bc][t] * A1[f'][t]   (M=2048,N=8192,K=1024)
  k_gemm_nt<<<1024, 256, 0, stream>>>(dm, A1, G, 1024, 1024, 8192, 1024, 0, 0);
  // P,Q from spectra (elementwise)
  k_pq<<<8192, 256, 0, stream>>>(G, scal, PQ);
  // GEMM2 split-K=8: partial[s][bc][t] = sum_{k in slice s} PQ[bc][k] * B2[t][k]
  k_gemm_nt<<<1024, 256, 0, stream>>>(PQ, B2, G, 8192, 8192, 1024, 128, 1024, 2097152);
  k_reduce8<<<2048, 256, 0, stream>>>(G, out, delta, ss4095);
  k_stats<<<2048, 256, 0, stream>>>(out, data, wt, nobs, invnf);
  k_final<<<(2048 * 1024) / 256, 256, 0, stream>>>(out, data, wt, invnf);
}

// Round 4
// 150.910 us; speedup vs baseline: 2.1742x; 1.3797x over previous
//
#include <hip/hip_runtime.h>
#include <hip/hip_bf16.h>

using bf16 = __hip_bfloat16;
typedef __attribute__((ext_vector_type(8))) short bf16x8;
typedef __attribute__((ext_vector_type(4))) short short4v;
typedef __attribute__((ext_vector_type(4))) float f32x4;

#define C_2PI_8192 7.6699039394282072e-4f

static __device__ __forceinline__ short bf16bits(float v) {
  bf16 h = __float2bfloat16(v);
  return *reinterpret_cast<short*>(&h);
}

#define GLOAD(gp, lp)                                                          \
  __builtin_amdgcn_global_load_lds(                                            \
      (const __attribute__((address_space(1))) void*)(gp),                     \
      (__attribute__((address_space(3))) void*)(lp), 16, 0, 0)

// ---------------- K1: mask dtype detect + wt build + nobs (single block) ------
__global__ __launch_bounds__(1024) void k_detect_wt(const void* __restrict__ mask,
                                                    float* __restrict__ wt,
                                                    float* __restrict__ nobs) {
  __shared__ int cnt;
  __shared__ float wsum[16];
  int tid = threadIdx.x;
  if (tid == 0) cnt = 0;
  __syncthreads();
  const unsigned char* mb = (const unsigned char*)mask;
  int c = 0;
#pragma unroll
  for (int i = 0; i < 4; ++i) c += (mb[tid * 4 + i] != 0) ? 1 : 0;
  atomicAdd(&cnt, c);
  __syncthreads();
  bool bytemode = (cnt > 2048);
  const int* mi = (const int*)mask;
  float s = 0.f;
#pragma unroll
  for (int i = 0; i < 4; ++i) {
    int e = tid * 4 + i;
    bool on = bytemode ? (mb[e] != 0) : (mi[e] != 0);
    float w = on ? 1.0f : 0.0f;
    wt[e] = w;
    s += w;
  }
#pragma unroll
  for (int m = 32; m; m >>= 1) s += __shfl_xor(s, m, 64);
  int wid = tid >> 6, lane = tid & 63;
  if (lane == 0) wsum[wid] = s;  // wave w covers e in [w*256,(w+1)*256) -> b=w>>2
  __syncthreads();
  if (tid < 4) nobs[tid] = wsum[tid * 4] + wsum[tid * 4 + 1] + wsum[tid * 4 + 2] + wsum[tid * 4 + 3];
}

// ---------------- K2: A1[f'][t] basis (t contiguous), bf16, 8 t per thread
__global__ void k_build_A1(bf16* __restrict__ A1) {
  int idx = blockIdx.x * blockDim.x + threadIdx.x;  // 8192*128
  int f = idx >> 7, t8 = (idx & 127) << 3;
  int fm = (f & 4095) + 1;
  bool is_sin = (f < 4096);
  int ph = (fm * (t8 + 1)) & 8191;
  short4v lo, hi;
#pragma unroll
  for (int j = 0; j < 8; ++j) {
    float x = ph * C_2PI_8192;
    float v = is_sin ? __sinf(x) : __cosf(x);
    if (j < 4) lo[j] = bf16bits(v); else hi[j - 4] = bf16bits(v);
    ph = (ph + fm) & 8191;
  }
  short* dst = (short*)&A1[((size_t)f << 10) + t8];
  *(short4v*)dst = lo;
  *(short4v*)(dst + 4) = hi;
}

// ---------------- K3: B2[t][k'] basis (k' contiguous), bf16, 8 k per thread
__global__ void k_build_B2(bf16* __restrict__ B2) {
  int idx = blockIdx.x * blockDim.x + threadIdx.x;  // 1024*1024
  int t = idx >> 10, k8 = (idx & 1023) << 3;
  int tp = t + 1;
  bool is_sin = (k8 < 4096);
  int km = (k8 & 4095) + 1;
  int ph = (km * tp) & 8191;
  short4v lo, hi;
#pragma unroll
  for (int j = 0; j < 8; ++j) {
    float x = ph * C_2PI_8192;
    float v = is_sin ? __sinf(x) : __cosf(x);
    if (j < 4) lo[j] = bf16bits(v); else hi[j - 4] = bf16bits(v);
    ph = (ph + tp) & 8191;
  }
  short* dst = (short*)&B2[((size_t)t << 13) + k8];
  *(short4v*)dst = lo;
  *(short4v*)(dst + 4) = hi;
}

// ---------------- K5: per-(b,f) tau stats -> {cos th, sin th, 1/den_s, 1/den_c}
__global__ __launch_bounds__(256) void k_tau(const float* __restrict__ wt,
                                             const float* __restrict__ nobs,
                                             float4* __restrict__ scal) {
  int gw = blockIdx.x * 4 + (threadIdx.x >> 6);  // one wave per (b,f)
  int lane = threadIdx.x & 63;
  int b = gw >> 12, f = gw & 4095;
  float num = 0.f, den = 0.f;
  int f2 = 2 * (f + 1);
  for (int t = lane; t < 1024; t += 64) {
    float w = wt[(b << 10) + t];
    int ph = (f2 * (t + 1)) & 8191;
    float x = ph * C_2PI_8192;
    num += w * __sinf(x);
    den += w * __cosf(x);
  }
#pragma unroll
  for (int m = 32; m; m >>= 1) {
    num += __shfl_xor(num, m, 64);
    den += __shfl_xor(den, m, 64);
  }
  if (lane == 0) {
    if (f == 4095) {
      // ang = pi: sin basis degenerate; handled by f32-replica fixup path.
      float nb = nobs[b];
      scal[gw] = make_float4(1.f, 0.f, 0.f, 1.f / nb);
    } else {
      float th = 0.5f * atan2f(num, den);
      float c = cosf(th), s = sinf(th);
      float nb = nobs[b];
      float WSS = 0.5f * (nb - den);
      float WCC = 0.5f * (nb + den);
      float WSC = 0.5f * num;
      float den_s = c * c * WSS - 2.f * c * s * WSC + s * s * WCC;
      float den_c = c * c * WCC + 2.f * c * s * WSC + s * s * WSS;
      scal[gw] = make_float4(c, s, 1.f / den_s, 1.f / den_c);
    }
  }
}

// ---------------- f=4095 fixup: replicate reference f32 arithmetic per b
__global__ __launch_bounds__(256) void k_f4095a(const float* __restrict__ wt,
                                                float* __restrict__ delta,
                                                float* __restrict__ invA) {
  const float W = (float)(6.283185307179586 / 8192.0);
  const float ang = W * 4096.0f;
  int b = threadIdx.x >> 6;
  int lane = threadIdx.x & 63;
  const float* wp = wt + (b << 10);
  float num = 0.f, den = 0.f;
  for (int t = lane; t < 1024; t += 64) {
    float tf = (float)(t + 1);
    float arg = ang * tf;
    float w = wp[t];
    num += w * sinf(2.0f * arg);
    den += w * cosf(2.0f * arg);
  }
#pragma unroll
  for (int m = 32; m; m >>= 1) {
    num += __shfl_xor(num, m, 64);
    den += __shfl_xor(den, m, 64);
  }
  float tau = atan2f(num, den) / (2.0f * ang);
  float P = ang * tau;
  float dss = 0.f;
  for (int t = lane; t < 1024; t += 64) {
    float tf = (float)(t + 1);
    float arg = ang * tf;
    float d = sinf(arg - P);
    delta[(b << 10) + t] = d;
    dss += wp[t] * d * d;
  }
#pragma unroll
  for (int m = 32; m; m >>= 1) dss += __shfl_xor(dss, m, 64);
  if (lane == 0) invA[b] = 1.f / dss;
}

// ---------------- K6: per-bc-row: dm = bf16(w*d) + data stats + f4095 dot
__global__ __launch_bounds__(256) void k_dm_stats(const float* __restrict__ data,
                                                  const float* __restrict__ wt,
                                                  const float* __restrict__ delta,
                                                  const float* __restrict__ invA,
                                                  bf16* __restrict__ dm,
                                                  float* __restrict__ sdv,
                                                  float* __restrict__ sd2v,
                                                  float* __restrict__ ss4095) {
  int bc = blockIdx.x, b = bc >> 9, tid = threadIdx.x;
  size_t base = (size_t)bc * 1024 + tid * 4;
  float4 d4 = *(const float4*)(data + base);
  float4 w4 = *(const float4*)(wt + (b << 10) + tid * 4);
  float4 e4 = *(const float4*)(delta + (b << 10) + tid * 4);
  const float* d = (const float*)&d4;
  const float* w = (const float*)&w4;
  const float* e = (const float*)&e4;
  short4v dmv;
  float sd = 0.f, sd2 = 0.f, sdd = 0.f;
#pragma unroll
  for (int j = 0; j < 4; ++j) {
    float wd = w[j] * d[j];
    dmv[j] = bf16bits(wd);
    sd += wd;
    sd2 += wd * d[j];
    sdd += wd * e[j];
  }
  *(short4v*)((short*)dm + base) = dmv;
#pragma unroll
  for (int m = 32; m; m >>= 1) {
    sd += __shfl_xor(sd, m, 64);
    sd2 += __shfl_xor(sd2, m, 64);
    sdd += __shfl_xor(sdd, m, 64);
  }
  __shared__ float red[4][3];
  int wid = tid >> 6, lane = tid & 63;
  if (lane == 0) { red[wid][0] = sd; red[wid][1] = sd2; red[wid][2] = sdd; }
  __syncthreads();
  if (tid == 0) {
    float a0 = 0, a1 = 0, a2 = 0;
#pragma unroll
    for (int ww = 0; ww < 4; ++ww) { a0 += red[ww][0]; a1 += red[ww][1]; a2 += red[ww][2]; }
    sdv[bc] = a0;
    sd2v[bc] = a1;
    ss4095[bc] = a2 * invA[b];
  }
}

// ---------------- GEMM1 + fused PQ epilogue ----------------
// C-tile: rows = 128 bc, cols = 64 f x {sin,cos} interleaved at 16-col granularity.
// LDS B row r <- A1 row 4096*((r>>4)&1) + f0 + (r&15) + ((r>>5)<<4).
// BK=64; 8-chunk rows, XOR-swizzle chunk c^(row&7) both sides.
__global__ __launch_bounds__(256, 4) void k_gemm1_pq(const bf16* __restrict__ dm,
                                                     const bf16* __restrict__ A1,
                                                     const float4* __restrict__ scal,
                                                     bf16* __restrict__ PQ) {
  __shared__ bf16 As[128 * 64];
  __shared__ bf16 Bs[128 * 64];
  int bid = blockIdx.x;
  int mt = bid & 15, ft = bid >> 4;
  int m0 = mt << 7, f0 = ft << 6;
  int tid = threadIdx.x, lane = tid & 63, wid = tid >> 6;
  int wm = (wid >> 1) << 6, wn = (wid & 1) << 6;
  int fr = lane & 15, kh = lane >> 4;

  int r0 = tid >> 3;
  int scol = ((tid & 7) ^ (r0 & 7)) << 3;
  const bf16* pa0 = dm + (size_t)(m0 + r0) * 1024 + scol;
  const bf16* pb[4];
#pragma unroll
  for (int n = 0; n < 4; ++n) {
    int row = n * 32 + r0;
    int gr = ((row >> 4) & 1) * 4096 + f0 + (row & 15) + ((row >> 5) << 4);
    pb[n] = A1 + (size_t)gr * 1024 + scol;
  }
  char* lA = (char*)As + (wid << 10);
  char* lB = (char*)Bs + (wid << 10);

  f32x4 acc[4][4] = {};
  int sw = fr & 7;

  for (int kt = 0; kt < 16; ++kt) {
#pragma unroll
    for (int n = 0; n < 4; ++n) {
      GLOAD(pa0 + n * 32768, lA + n * 4096);
      GLOAD(pb[n], lB + n * 4096);
      pb[n] += 64;
    }
    pa0 += 64;
    __syncthreads();
#pragma unroll
    for (int s = 0; s < 2; ++s) {
      bf16x8 a[4];
#pragma unroll
      for (int i = 0; i < 4; ++i)
        a[i] = *(const bf16x8*)&As[(wm + i * 16 + fr) * 64 + ((((s << 2) + kh) ^ sw) << 3)];
#pragma unroll
      for (int j = 0; j < 4; ++j) {
        bf16x8 bb = *(const bf16x8*)&Bs[(wn + j * 16 + fr) * 64 + ((((s << 2) + kh) ^ sw) << 3)];
#pragma unroll
        for (int i = 0; i < 4; ++i)
          acc[i][j] = __builtin_amdgcn_mfma_f32_16x16x32_bf16(a[i], bb, acc[i][j], 0, 0, 0);
      }
    }
    __syncthreads();
  }
  // epilogue: pairs (j=2p, 2p+1) = (GS, GC) at f = f0 + (wn>>1) + p*16 + fr
  int b = m0 >> 9;
  short* pq = (short*)PQ;
#pragma unroll
  for (int p = 0; p < 2; ++p) {
    int f = f0 + (wn >> 1) + (p << 4) + fr;
    float4 sc = scal[(b << 12) + f];
    float c = sc.x, s = sc.y, ids = sc.z, idc = sc.w;
#pragma unroll
    for (int i = 0; i < 4; ++i) {
#pragma unroll
      for (int q = 0; q < 4; ++q) {
        int bc = m0 + wm + i * 16 + (kh << 2) + q;
        float GS = acc[i][2 * p][q], GC = acc[i][2 * p + 1][q];
        float ss = (c * GS - s * GC) * ids;
        float cs = (c * GC + s * GS) * idc;
        pq[(size_t)bc * 8192 + f] = bf16bits(c * ss + s * cs);
        pq[(size_t)bc * 8192 + 4096 + f] = bf16bits(c * cs - s * ss);
      }
    }
  }
}

// ---------------- GEMM2 (NT, split-K=8): partial[s][bc][t] ----------------
__global__ __launch_bounds__(256, 4) void k_gemm2(const bf16* __restrict__ PQ,
                                                  const bf16* __restrict__ B2,
                                                  float* __restrict__ G) {
  __shared__ bf16 As[128 * 64];
  __shared__ bf16 Bs[128 * 64];
  int bid = blockIdx.x;
  int slice = bid >> 7, tl = bid & 127;
  int mt = tl & 15, nt = tl >> 4;
  int m0 = mt << 7, n0 = nt << 7;
  int tid = threadIdx.x, lane = tid & 63, wid = tid >> 6;
  int wm = (wid >> 1) << 6, wn = (wid & 1) << 6;
  int fr = lane & 15, kh = lane >> 4;

  int r0 = tid >> 3;
  int scol = ((tid & 7) ^ (r0 & 7)) << 3;
  const bf16* pa0 = PQ + (size_t)slice * 1024 + (size_t)(m0 + r0) * 8192 + scol;
  const bf16* pb0 = B2 + (size_t)slice * 1024 + (size_t)(n0 + r0) * 8192 + scol;
  float* C = G + (size_t)slice * 2097152;
  char* lA = (char*)As + (wid << 10);
  char* lB = (char*)Bs + (wid << 10);

  f32x4 acc[4][4] = {};
  int sw = fr & 7;

  for (int kt = 0; kt < 16; ++kt) {
#pragma unroll
    for (int n = 0; n < 4; ++n) {
      GLOAD(pa0 + n * 262144, lA + n * 4096);
      GLOAD(pb0 + n * 262144, lB + n * 4096);
    }
    pa0 += 64; pb0 += 64;
    __syncthreads();
#pragma unroll
    for (int s = 0; s < 2; ++s) {
      bf16x8 a[4];
#pragma unroll
      for (int i = 0; i < 4; ++i)
        a[i] = *(const bf16x8*)&As[(wm + i * 16 + fr) * 64 + ((((s << 2) + kh) ^ sw) << 3)];
#pragma unroll
      for (int j = 0; j < 4; ++j) {
        bf16x8 bb = *(const bf16x8*)&Bs[(wn + j * 16 + fr) * 64 + ((((s << 2) + kh) ^ sw) << 3)];
#pragma unroll
        for (int i = 0; i < 4; ++i)
          acc[i][j] = __builtin_amdgcn_mfma_f32_16x16x32_bf16(a[i], bb, acc[i][j], 0, 0, 0);
      }
    }
    __syncthreads();
  }
#pragma unroll
  for (int i = 0; i < 4; ++i) {
#pragma unroll
    for (int q = 0; q < 4; ++q) {
      size_t row = m0 + wm + i * 16 + (kh << 2) + q;
      float* cp = C + row * 1024 + n0 + wn + fr;
#pragma unroll
      for (int j = 0; j < 4; ++j) cp[j * 16] = acc[i][j][q];
    }
  }
}

// ---------------- K-tail: reduce partials + f4095 corr + stats + final select
__global__ __launch_bounds__(256) void k_tail(const float* __restrict__ G,
                                              const float* __restrict__ data,
                                              const float* __restrict__ wt,
                                              const float* __restrict__ delta,
                                              const float* __restrict__ ss4095,
                                              const float* __restrict__ sdv,
                                              const float* __restrict__ sd2v,
                                              const float* __restrict__ nobs,
                                              float* __restrict__ out) {
  int bc = blockIdx.x, b = bc >> 9, tid = threadIdx.x;
  size_t base = (size_t)bc * 1024 + tid * 4;
  float r[4] = {0.f, 0.f, 0.f, 0.f};
#pragma unroll
  for (int sl = 0; sl < 8; ++sl) {
    float4 v = *(const float4*)(G + (size_t)sl * 2097152 + base);
    r[0] += v.x; r[1] += v.y; r[2] += v.z; r[3] += v.w;
  }
  float ssv = ss4095[bc];
  float4 e4 = *(const float4*)(delta + (b << 10) + tid * 4);
  float4 w4 = *(const float4*)(wt + (b << 10) + tid * 4);
  float4 d4 = *(const float4*)(data + base);
  const float* e = (const float*)&e4;
  const float* w = (const float*)&w4;
  const float* d = (const float*)&d4;
  float sr = 0.f, sr2 = 0.f;
#pragma unroll
  for (int j = 0; j < 4; ++j) {
    r[j] += e[j] * ssv;
    float wr = w[j] * r[j];
    sr += wr;
    sr2 += wr * r[j];
  }
#pragma unroll
  for (int m = 32; m; m >>= 1) {
    sr += __shfl_xor(sr, m, 64);
    sr2 += __shfl_xor(sr2, m, 64);
  }
  __shared__ float red[4][2];
  __shared__ float s_inv;
  int wid = tid >> 6, lane = tid & 63;
  if (lane == 0) { red[wid][0] = sr; red[wid][1] = sr2; }
  __syncthreads();
  if (tid == 0) {
    float a0 = 0, a1 = 0;
#pragma unroll
    for (int ww = 0; ww < 4; ++ww) { a0 += red[ww][0]; a1 += red[ww][1]; }
    float n = nobs[b];
    float mr = a0 / n, vr = (a1 - n * mr * mr) / (n - 1.f);
    float md = sdv[bc] / n, vd = (sd2v[bc] - n * md * md) / (n - 1.f);
    s_inv = sqrtf(vd / vr);
  }
  __syncthreads();
  float inv = s_inv;
  float4 o;
  ((float*)&o)[0] = (w[0] != 0.f) ? d[0] : r[0] * inv;
  ((float*)&o)[1] = (w[1] != 0.f) ? d[1] : r[1] * inv;
  ((float*)&o)[2] = (w[2] != 0.f) ? d[2] : r[2] * inv;
  ((float*)&o)[3] = (w[3] != 0.f) ? d[3] : r[3] * inv;
  *(float4*)(out + base) = o;
}

extern "C" void kernel_launch(void* const* d_in, const int* in_sizes, int n_in,
                              void* d_out, int out_size, void* d_ws, size_t ws_size,
                              hipStream_t stream) {
  const float* data = (const float*)d_in[0];
  const void* mask = d_in[1];
  float* out = (float*)d_out;
  char* ws = (char*)d_ws;

  float* wt = (float*)(ws);                 // 16 KB
  float* nobs = (float*)(ws + 16384);       // 16 B
  float4* scal = (float4*)(ws + 32768);     // 256 KB
  float* delta = (float*)(ws + 303104);     // 16 KB
  float* ss4095 = (float*)(ws + 319488);    // 8 KB
  float* invA = (float*)(ws + 327680);      // 16 B
  float* sdv = (float*)(ws + 331776);       // 8 KB
  float* sd2v = (float*)(ws + 339968);      // 8 KB
  const size_t MB = 1ull << 20;
  bf16* A1 = (bf16*)(ws + 1 * MB);    // 8192x1024 bf16 = 16 MB  [f'][t]
  bf16* B2 = (bf16*)(ws + 17 * MB);   // 1024x8192 bf16 = 16 MB  [t][k']
  bf16* dm = (bf16*)(ws + 33 * MB);   // 2048x1024 bf16 = 4 MB
  float* G = (float*)(ws + 37 * MB);  // 8 x 2M f32 = 64 MB split-K partials
  bf16* PQ = (bf16*)(ws + 101 * MB);  // 2048x8192 bf16 = 32 MB  [bc][k']

  k_detect_wt<<<1, 1024, 0, stream>>>(mask, wt, nobs);
  k_f4095a<<<1, 256, 0, stream>>>(wt, delta, invA);
  k_build_A1<<<4096, 256, 0, stream>>>(A1);
  k_build_B2<<<4096, 256, 0, stream>>>(B2);
  k_tau<<<4096, 256, 0, stream>>>(wt, nobs, scal);
  k_dm_stats<<<2048, 256, 0, stream>>>(data, wt, delta, invA, dm, sdv, sd2v, ss4095);
  // GEMM1 + PQ epilogue: (M=2048 bc, 64 ftiles x {sin,cos}, K=1024)
  k_gemm1_pq<<<1024, 256, 0, stream>>>(dm, A1, scal, PQ);
  // GEMM2 split-K=8: partial[s][bc][t] = sum_{k in slice} PQ[bc][k]*B2[t][k]
  k_gemm2<<<1024, 256, 0, stream>>>(PQ, B2, G);
  k_tail<<<2048, 256, 0, stream>>>(G, data, wt, delta, ss4095, sdv, sd2v, nobs, out);
}

// Round 5
// 132.335 us; speedup vs baseline: 2.4794x; 1.1404x over previous
//
#include <hip/hip_runtime.h>
#include <hip/hip_bf16.h>
#include <hip/hip_fp16.h>

using bf16 = __hip_bfloat16;
typedef __attribute__((ext_vector_type(8))) short bf16x8;
typedef __attribute__((ext_vector_type(4))) short short4v;
typedef __attribute__((ext_vector_type(4))) float f32x4;
typedef __attribute__((ext_vector_type(4))) _Float16 halfx4;

#define C_2PI_8192 7.6699039394282072e-4f

static __device__ __forceinline__ short bf16bits(float v) {
  bf16 h = __float2bfloat16(v);
  return *reinterpret_cast<short*>(&h);
}

#define GLOAD(gp, lp)                                                          \
  __builtin_amdgcn_global_load_lds(                                            \
      (const __attribute__((address_space(1))) void*)(gp),                     \
      (__attribute__((address_space(3))) void*)(lp), 16, 0, 0)

// ---------------- K1: mask detect + wt + nobs, then f=4095 f32-replica fixup --
__global__ __launch_bounds__(1024) void k_prep(const void* __restrict__ mask,
                                               float* __restrict__ wt,
                                               float* __restrict__ nobs,
                                               float* __restrict__ delta,
                                               float* __restrict__ invA) {
  __shared__ int cnt;
  __shared__ float wsum[16];
  int tid = threadIdx.x;
  if (tid == 0) cnt = 0;
  __syncthreads();
  const unsigned char* mb = (const unsigned char*)mask;
  int c = 0;
#pragma unroll
  for (int i = 0; i < 4; ++i) c += (mb[tid * 4 + i] != 0) ? 1 : 0;
  atomicAdd(&cnt, c);
  __syncthreads();
  bool bytemode = (cnt > 2048);
  const int* mi = (const int*)mask;
  float s = 0.f;
#pragma unroll
  for (int i = 0; i < 4; ++i) {
    int e = tid * 4 + i;
    bool on = bytemode ? (mb[e] != 0) : (mi[e] != 0);
    float w = on ? 1.0f : 0.0f;
    wt[e] = w;
    s += w;
  }
#pragma unroll
  for (int m = 32; m; m >>= 1) s += __shfl_xor(s, m, 64);
  int wid = tid >> 6, lane = tid & 63;
  if (lane == 0) wsum[wid] = s;
  __syncthreads();
  if (tid < 4) nobs[tid] = wsum[tid * 4] + wsum[tid * 4 + 1] + wsum[tid * 4 + 2] + wsum[tid * 4 + 3];
  __syncthreads();
  // ---- f=4095 fixup: replicate reference f32 arithmetic per b (waves 0-3) ----
  if (tid < 256) {
    const float W = (float)(6.283185307179586 / 8192.0);
    const float ang = W * 4096.0f;
    int b = tid >> 6;
    const float* wp = wt + (b << 10);
    float num = 0.f, den = 0.f;
    for (int t = lane; t < 1024; t += 64) {
      float tf = (float)(t + 1);
      float arg = ang * tf;
      float w = wp[t];
      num += w * sinf(2.0f * arg);
      den += w * cosf(2.0f * arg);
    }
#pragma unroll
    for (int m = 32; m; m >>= 1) {
      num += __shfl_xor(num, m, 64);
      den += __shfl_xor(den, m, 64);
    }
    float tau = atan2f(num, den) / (2.0f * ang);
    float P = ang * tau;
    float dss = 0.f;
    for (int t = lane; t < 1024; t += 64) {
      float tf = (float)(t + 1);
      float arg = ang * tf;
      float d = sinf(arg - P);
      delta[(b << 10) + t] = d;
      dss += wp[t] * d * d;
    }
#pragma unroll
    for (int m = 32; m; m >>= 1) dss += __shfl_xor(dss, m, 64);
    if (lane == 0) invA[b] = 1.f / dss;
  }
}

// ---------------- K2: basis builds, A1[f'][t] (bid<4096) and B2[t][k'] --------
__global__ void k_build(bf16* __restrict__ A1, bf16* __restrict__ B2) {
  int bid = blockIdx.x;
  if (bid < 4096) {
    int idx = bid * 256 + threadIdx.x;  // 8192*128
    int f = idx >> 7, t8 = (idx & 127) << 3;
    int fm = (f & 4095) + 1;
    bool is_sin = (f < 4096);
    int ph = (fm * (t8 + 1)) & 8191;
    short4v lo, hi;
#pragma unroll
    for (int j = 0; j < 8; ++j) {
      float x = ph * C_2PI_8192;
      float v = is_sin ? __sinf(x) : __cosf(x);
      if (j < 4) lo[j] = bf16bits(v); else hi[j - 4] = bf16bits(v);
      ph = (ph + fm) & 8191;
    }
    short* dst = (short*)&A1[((size_t)f << 10) + t8];
    *(short4v*)dst = lo;
    *(short4v*)(dst + 4) = hi;
  } else {
    int idx = (bid - 4096) * 256 + threadIdx.x;  // 1024*1024
    int t = idx >> 10, k8 = (idx & 1023) << 3;
    int tp = t + 1;
    bool is_sin = (k8 < 4096);
    int km = (k8 & 4095) + 1;
    int ph = (km * tp) & 8191;
    short4v lo, hi;
#pragma unroll
    for (int j = 0; j < 8; ++j) {
      float x = ph * C_2PI_8192;
      float v = is_sin ? __sinf(x) : __cosf(x);
      if (j < 4) lo[j] = bf16bits(v); else hi[j - 4] = bf16bits(v);
      ph = (ph + tp) & 8191;
    }
    short* dst = (short*)&B2[((size_t)t << 13) + k8];
    *(short4v*)dst = lo;
    *(short4v*)(dst + 4) = hi;
  }
}

// ---------------- K3: tau/scal (bid<4096) and dm+stats (bid>=4096) ------------
__global__ __launch_bounds__(256) void k_mid(const float* __restrict__ wt,
                                             const float* __restrict__ nobs,
                                             const float* __restrict__ data,
                                             const float* __restrict__ delta,
                                             const float* __restrict__ invA,
                                             float4* __restrict__ scal,
                                             bf16* __restrict__ dm,
                                             float* __restrict__ sdv,
                                             float* __restrict__ sd2v,
                                             float* __restrict__ ss4095) {
  int bid = blockIdx.x, tid = threadIdx.x;
  int wid = tid >> 6, lane = tid & 63;
  if (bid < 4096) {
    // per-(b,f): {cos th, sin th, 1/den_s, 1/den_c}
    int gw = bid * 4 + wid;
    int b = gw >> 12, f = gw & 4095;
    float num = 0.f, den = 0.f;
    int f2 = 2 * (f + 1);
    for (int t = lane; t < 1024; t += 64) {
      float w = wt[(b << 10) + t];
      int ph = (f2 * (t + 1)) & 8191;
      float x = ph * C_2PI_8192;
      num += w * __sinf(x);
      den += w * __cosf(x);
    }
#pragma unroll
    for (int m = 32; m; m >>= 1) {
      num += __shfl_xor(num, m, 64);
      den += __shfl_xor(den, m, 64);
    }
    if (lane == 0) {
      if (f == 4095) {
        float nb = nobs[b];
        scal[gw] = make_float4(1.f, 0.f, 0.f, 1.f / nb);
      } else {
        float th = 0.5f * atan2f(num, den);
        float c = cosf(th), s = sinf(th);
        float nb = nobs[b];
        float WSS = 0.5f * (nb - den);
        float WCC = 0.5f * (nb + den);
        float WSC = 0.5f * num;
        float den_s = c * c * WSS - 2.f * c * s * WSC + s * s * WCC;
        float den_c = c * c * WCC + 2.f * c * s * WSC + s * s * WSS;
        scal[gw] = make_float4(c, s, 1.f / den_s, 1.f / den_c);
      }
    }
  } else {
    // per-bc row: dm = bf16(w*d), data stats, f4095 dot
    int bc = bid - 4096, b = bc >> 9;
    size_t base = (size_t)bc * 1024 + tid * 4;
    float4 d4 = *(const float4*)(data + base);
    float4 w4 = *(const float4*)(wt + (b << 10) + tid * 4);
    float4 e4 = *(const float4*)(delta + (b << 10) + tid * 4);
    const float* d = (const float*)&d4;
    const float* w = (const float*)&w4;
    const float* e = (const float*)&e4;
    short4v dmv;
    float sd = 0.f, sd2 = 0.f, sdd = 0.f;
#pragma unroll
    for (int j = 0; j < 4; ++j) {
      float wd = w[j] * d[j];
      dmv[j] = bf16bits(wd);
      sd += wd;
      sd2 += wd * d[j];
      sdd += wd * e[j];
    }
    *(short4v*)((short*)dm + base) = dmv;
#pragma unroll
    for (int m = 32; m; m >>= 1) {
      sd += __shfl_xor(sd, m, 64);
      sd2 += __shfl_xor(sd2, m, 64);
      sdd += __shfl_xor(sdd, m, 64);
    }
    __shared__ float red[4][3];
    if (lane == 0) { red[wid][0] = sd; red[wid][1] = sd2; red[wid][2] = sdd; }
    __syncthreads();
    if (tid == 0) {
      float a0 = 0, a1 = 0, a2 = 0;
#pragma unroll
      for (int ww = 0; ww < 4; ++ww) { a0 += red[ww][0]; a1 += red[ww][1]; a2 += red[ww][2]; }
      sdv[bc] = a0;
      sd2v[bc] = a1;
      ss4095[bc] = a2 * invA[b];
    }
  }
}

// ---------------- GEMM1 + fused PQ epilogue ----------------
// C-tile: rows = 128 bc, cols = 64 f x {sin,cos} interleaved at 16-col granularity.
// LDS B row r <- A1 row 4096*((r>>4)&1) + f0 + (r&15) + ((r>>5)<<4).
// BK=64; 8-chunk rows, XOR-swizzle chunk c^(row&7) both sides. XCD-swizzled grid.
__global__ __launch_bounds__(256, 4) void k_gemm1_pq(const bf16* __restrict__ dm,
                                                     const bf16* __restrict__ A1,
                                                     const float4* __restrict__ scal,
                                                     bf16* __restrict__ PQ) {
  __shared__ bf16 As[128 * 64];
  __shared__ bf16 Bs[128 * 64];
  int bid = blockIdx.x;
  int swz = ((bid & 7) << 7) | (bid >> 3);  // 1024 blocks, 8 XCDs, bijective
  int mt = swz & 15, ft = swz >> 4;
  int m0 = mt << 7, f0 = ft << 6;
  int tid = threadIdx.x, lane = tid & 63, wid = tid >> 6;
  int wm = (wid >> 1) << 6, wn = (wid & 1) << 6;
  int fr = lane & 15, kh = lane >> 4;

  int r0 = tid >> 3;
  int scol = ((tid & 7) ^ (r0 & 7)) << 3;
  const bf16* pa0 = dm + (size_t)(m0 + r0) * 1024 + scol;
  const bf16* pb[4];
#pragma unroll
  for (int n = 0; n < 4; ++n) {
    int row = n * 32 + r0;
    int gr = ((row >> 4) & 1) * 4096 + f0 + (row & 15) + ((row >> 5) << 4);
    pb[n] = A1 + (size_t)gr * 1024 + scol;
  }
  char* lA = (char*)As + (wid << 10);
  char* lB = (char*)Bs + (wid << 10);

  f32x4 acc[4][4] = {};
  int sw = fr & 7;

  for (int kt = 0; kt < 16; ++kt) {
#pragma unroll
    for (int n = 0; n < 4; ++n) {
      GLOAD(pa0 + n * 32768, lA + n * 4096);
      GLOAD(pb[n], lB + n * 4096);
      pb[n] += 64;
    }
    pa0 += 64;
    __syncthreads();
#pragma unroll
    for (int s = 0; s < 2; ++s) {
      bf16x8 a[4];
#pragma unroll
      for (int i = 0; i < 4; ++i)
        a[i] = *(const bf16x8*)&As[(wm + i * 16 + fr) * 64 + ((((s << 2) + kh) ^ sw) << 3)];
#pragma unroll
      for (int j = 0; j < 4; ++j) {
        bf16x8 bb = *(const bf16x8*)&Bs[(wn + j * 16 + fr) * 64 + ((((s << 2) + kh) ^ sw) << 3)];
#pragma unroll
        for (int i = 0; i < 4; ++i)
          acc[i][j] = __builtin_amdgcn_mfma_f32_16x16x32_bf16(a[i], bb, acc[i][j], 0, 0, 0);
      }
    }
    __syncthreads();
  }
  // epilogue: pairs (j=2p, 2p+1) = (GS, GC) at f = f0 + (wn>>1) + p*16 + fr
  int b = m0 >> 9;
  short* pq = (short*)PQ;
#pragma unroll
  for (int p = 0; p < 2; ++p) {
    int f = f0 + (wn >> 1) + (p << 4) + fr;
    float4 sc = scal[(b << 12) + f];
    float c = sc.x, s = sc.y, ids = sc.z, idc = sc.w;
#pragma unroll
    for (int i = 0; i < 4; ++i) {
#pragma unroll
      for (int q = 0; q < 4; ++q) {
        int bc = m0 + wm + i * 16 + (kh << 2) + q;
        float GS = acc[i][2 * p][q], GC = acc[i][2 * p + 1][q];
        float ss = (c * GS - s * GC) * ids;
        float cs = (c * GC + s * GS) * idc;
        pq[(size_t)bc * 8192 + f] = bf16bits(c * ss + s * cs);
        pq[(size_t)bc * 8192 + 4096 + f] = bf16bits(c * cs - s * ss);
      }
    }
  }
}

// ---------------- GEMM2 (NT, split-K=8, fp16 partials): partial[s][bc][t] -----
__global__ __launch_bounds__(256, 4) void k_gemm2(const bf16* __restrict__ PQ,
                                                  const bf16* __restrict__ B2,
                                                  _Float16* __restrict__ G) {
  __shared__ bf16 As[128 * 64];
  __shared__ bf16 Bs[128 * 64];
  int bid = blockIdx.x;
  int swz = ((bid & 7) << 7) | (bid >> 3);  // XCD s gets slice s entirely
  int slice = swz >> 7, tl = swz & 127;
  int mt = tl & 15, nt = tl >> 4;
  int m0 = mt << 7, n0 = nt << 7;
  int tid = threadIdx.x, lane = tid & 63, wid = tid >> 6;
  int wm = (wid >> 1) << 6, wn = (wid & 1) << 6;
  int fr = lane & 15, kh = lane >> 4;

  int r0 = tid >> 3;
  int scol = ((tid & 7) ^ (r0 & 7)) << 3;
  const bf16* pa0 = PQ + (size_t)slice * 1024 + (size_t)(m0 + r0) * 8192 + scol;
  const bf16* pb0 = B2 + (size_t)slice * 1024 + (size_t)(n0 + r0) * 8192 + scol;
  _Float16* C = G + (size_t)slice * 2097152;
  char* lA = (char*)As + (wid << 10);
  char* lB = (char*)Bs + (wid << 10);

  f32x4 acc[4][4] = {};
  int sw = fr & 7;

  for (int kt = 0; kt < 16; ++kt) {
#pragma unroll
    for (int n = 0; n < 4; ++n) {
      GLOAD(pa0 + n * 262144, lA + n * 4096);
      GLOAD(pb0 + n * 262144, lB + n * 4096);
    }
    pa0 += 64; pb0 += 64;
    __syncthreads();
#pragma unroll
    for (int s = 0; s < 2; ++s) {
      bf16x8 a[4];
#pragma unroll
      for (int i = 0; i < 4; ++i)
        a[i] = *(const bf16x8*)&As[(wm + i * 16 + fr) * 64 + ((((s << 2) + kh) ^ sw) << 3)];
#pragma unroll
      for (int j = 0; j < 4; ++j) {
        bf16x8 bb = *(const bf16x8*)&Bs[(wn + j * 16 + fr) * 64 + ((((s << 2) + kh) ^ sw) << 3)];
#pragma unroll
        for (int i = 0; i < 4; ++i)
          acc[i][j] = __builtin_amdgcn_mfma_f32_16x16x32_bf16(a[i], bb, acc[i][j], 0, 0, 0);
      }
    }
    __syncthreads();
  }
#pragma unroll
  for (int i = 0; i < 4; ++i) {
#pragma unroll
    for (int q = 0; q < 4; ++q) {
      size_t row = m0 + wm + i * 16 + (kh << 2) + q;
      _Float16* cp = C + row * 1024 + n0 + wn + fr;
#pragma unroll
      for (int j = 0; j < 4; ++j) cp[j * 16] = (_Float16)acc[i][j][q];
    }
  }
}

// ---------------- K-tail: reduce partials + f4095 corr + stats + final select
__global__ __launch_bounds__(256) void k_tail(const _Float16* __restrict__ G,
                                              const float* __restrict__ data,
                                              const float* __restrict__ wt,
                                              const float* __restrict__ delta,
                                              const float* __restrict__ ss4095,
                                              const float* __restrict__ sdv,
                                              const float* __restrict__ sd2v,
                                              const float* __restrict__ nobs,
                                              float* __restrict__ out) {
  int bc = blockIdx.x, b = bc >> 9, tid = threadIdx.x;
  size_t base = (size_t)bc * 1024 + tid * 4;
  float r[4] = {0.f, 0.f, 0.f, 0.f};
#pragma unroll
  for (int sl = 0; sl < 8; ++sl) {
    halfx4 v = *(const halfx4*)(G + (size_t)sl * 2097152 + base);
#pragma unroll
    for (int j = 0; j < 4; ++j) r[j] += (float)v[j];
  }
  float ssv = ss4095[bc];
  float4 e4 = *(const float4*)(delta + (b << 10) + tid * 4);
  float4 w4 = *(const float4*)(wt + (b << 10) + tid * 4);
  float4 d4 = *(const float4*)(data + base);
  const float* e = (const float*)&e4;
  const float* w = (const float*)&w4;
  const float* d = (const float*)&d4;
  float sr = 0.f, sr2 = 0.f;
#pragma unroll
  for (int j = 0; j < 4; ++j) {
    r[j] += e[j] * ssv;
    float wr = w[j] * r[j];
    sr += wr;
    sr2 += wr * r[j];
  }
#pragma unroll
  for (int m = 32; m; m >>= 1) {
    sr += __shfl_xor(sr, m, 64);
    sr2 += __shfl_xor(sr2, m, 64);
  }
  __shared__ float red[4][2];
  __shared__ float s_inv;
  int wid = tid >> 6, lane = tid & 63;
  if (lane == 0) { red[wid][0] = sr; red[wid][1] = sr2; }
  __syncthreads();
  if (tid == 0) {
    float a0 = 0, a1 = 0;
#pragma unroll
    for (int ww = 0; ww < 4; ++ww) { a0 += red[ww][0]; a1 += red[ww][1]; }
    float n = nobs[b];
    float mr = a0 / n, vr = (a1 - n * mr * mr) / (n - 1.f);
    float md = sdv[bc] / n, vd = (sd2v[bc] - n * md * md) / (n - 1.f);
    s_inv = sqrtf(vd / vr);
  }
  __syncthreads();
  float inv = s_inv;
  float4 o;
  ((float*)&o)[0] = (w[0] != 0.f) ? d[0] : r[0] * inv;
  ((float*)&o)[1] = (w[1] != 0.f) ? d[1] : r[1] * inv;
  ((float*)&o)[2] = (w[2] != 0.f) ? d[2] : r[2] * inv;
  ((float*)&o)[3] = (w[3] != 0.f) ? d[3] : r[3] * inv;
  *(float4*)(out + base) = o;
}

extern "C" void kernel_launch(void* const* d_in, const int* in_sizes, int n_in,
                              void* d_out, int out_size, void* d_ws, size_t ws_size,
                              hipStream_t stream) {
  const float* data = (const float*)d_in[0];
  const void* mask = d_in[1];
  float* out = (float*)d_out;
  char* ws = (char*)d_ws;

  float* wt = (float*)(ws);                 // 16 KB
  float* nobs = (float*)(ws + 16384);       // 16 B
  float4* scal = (float4*)(ws + 32768);     // 256 KB
  float* delta = (float*)(ws + 303104);     // 16 KB
  float* ss4095 = (float*)(ws + 319488);    // 8 KB
  float* invA = (float*)(ws + 327680);      // 16 B
  float* sdv = (float*)(ws + 331776);       // 8 KB
  float* sd2v = (float*)(ws + 339968);      // 8 KB
  const size_t MB = 1ull << 20;
  bf16* A1 = (bf16*)(ws + 1 * MB);          // 8192x1024 bf16 = 16 MB  [f'][t]
  bf16* B2 = (bf16*)(ws + 17 * MB);         // 1024x8192 bf16 = 16 MB  [t][k']
  bf16* dm = (bf16*)(ws + 33 * MB);         // 2048x1024 bf16 = 4 MB
  _Float16* G = (_Float16*)(ws + 37 * MB);  // 8 x 2M fp16 = 32 MB split-K partials
  bf16* PQ = (bf16*)(ws + 101 * MB);        // 2048x8192 bf16 = 32 MB  [bc][k']

  k_prep<<<1, 1024, 0, stream>>>(mask, wt, nobs, delta, invA);
  k_build<<<8192, 256, 0, stream>>>(A1, B2);
  k_mid<<<6144, 256, 0, stream>>>(wt, nobs, data, delta, invA, scal, dm, sdv, sd2v, ss4095);
  // GEMM1 + PQ epilogue: (M=2048 bc, 64 ftiles x {sin,cos}, K=1024)
  k_gemm1_pq<<<1024, 256, 0, stream>>>(dm, A1, scal, PQ);
  // GEMM2 split-K=8: partial[s][bc][t] = sum_{k in slice} PQ[bc][k]*B2[t][k]
  k_gemm2<<<1024, 256, 0, stream>>>(PQ, B2, G);
  k_tail<<<2048, 256, 0, stream>>>(G, data, wt, delta, ss4095, sdv, sd2v, nobs, out);
}

// Round 6
// 102.244 us; speedup vs baseline: 3.2091x; 1.2943x over previous
//
#include <hip/hip_runtime.h>
#include <hip/hip_bf16.h>
#include <hip/hip_fp16.h>

using bf16 = __hip_bfloat16;
typedef __attribute__((ext_vector_type(8))) short bf16x8;
typedef __attribute__((ext_vector_type(4))) short short4v;
typedef __attribute__((ext_vector_type(2))) short short2v;
typedef __attribute__((ext_vector_type(4))) float f32x4;
typedef __attribute__((ext_vector_type(2))) _Float16 halfx2;

#define C_2PI_8192 7.6699039394282072e-4f

static __device__ __forceinline__ short bf16bits(float v) {
  bf16 h = __float2bfloat16(v);
  return *reinterpret_cast<short*>(&h);
}

#define GLOAD(gp, lp)                                                          \
  __builtin_amdgcn_global_load_lds(                                            \
      (const __attribute__((address_space(1))) void*)(gp),                     \
      (__attribute__((address_space(3))) void*)(lp), 16, 0, 0)

// ---------------- K1: mask detect + wt + nobs + f=4095 sin f32-replica fixup --
__global__ __launch_bounds__(1024) void k_prep(const void* __restrict__ mask,
                                               float* __restrict__ wt,
                                               float* __restrict__ nobs,
                                               float* __restrict__ delta,
                                               float* __restrict__ invA) {
  __shared__ int cnt;
  __shared__ float wsum[16];
  int tid = threadIdx.x;
  if (tid == 0) cnt = 0;
  __syncthreads();
  const unsigned char* mb = (const unsigned char*)mask;
  int c = 0;
#pragma unroll
  for (int i = 0; i < 4; ++i) c += (mb[tid * 4 + i] != 0) ? 1 : 0;
  atomicAdd(&cnt, c);
  __syncthreads();
  bool bytemode = (cnt > 2048);
  const int* mi = (const int*)mask;
  float s = 0.f;
#pragma unroll
  for (int i = 0; i < 4; ++i) {
    int e = tid * 4 + i;
    bool on = bytemode ? (mb[e] != 0) : (mi[e] != 0);
    float w = on ? 1.0f : 0.0f;
    wt[e] = w;
    s += w;
  }
#pragma unroll
  for (int m = 32; m; m >>= 1) s += __shfl_xor(s, m, 64);
  int wid = tid >> 6, lane = tid & 63;
  if (lane == 0) wsum[wid] = s;
  __syncthreads();
  if (tid < 4) nobs[tid] = wsum[tid * 4] + wsum[tid * 4 + 1] + wsum[tid * 4 + 2] + wsum[tid * 4 + 3];
  __syncthreads();
  if (tid < 256) {
    const float W = (float)(6.283185307179586 / 8192.0);
    const float ang = W * 4096.0f;
    int b = tid >> 6;
    const float* wp = wt + (b << 10);
    float num = 0.f, den = 0.f;
    for (int t = lane; t < 1024; t += 64) {
      float tf = (float)(t + 1);
      float arg = ang * tf;
      float w = wp[t];
      num += w * sinf(2.0f * arg);
      den += w * cosf(2.0f * arg);
    }
#pragma unroll
    for (int m = 32; m; m >>= 1) {
      num += __shfl_xor(num, m, 64);
      den += __shfl_xor(den, m, 64);
    }
    float tau = atan2f(num, den) / (2.0f * ang);
    float P = ang * tau;
    float dss = 0.f;
    for (int t = lane; t < 1024; t += 64) {
      float tf = (float)(t + 1);
      float arg = ang * tf;
      float d = sinf(arg - P);
      delta[(b << 10) + t] = d;
      dss += wp[t] * d * d;
    }
#pragma unroll
    for (int m = 32; m; m >>= 1) dss += __shfl_xor(dss, m, 64);
    if (lane == 0) invA[b] = 1.f / dss;
  }
}

// ---------------- K2: basis tables (m in [1,2048]; even/odd tau halves) -------
__global__ void k_build(bf16* __restrict__ AE, bf16* __restrict__ Be) {
  int bid = blockIdx.x;
  int region = bid >> 10;
  int idx = (bid & 1023) * 256 + threadIdx.x;
  short4v lo, hi;
  if (region < 2) {
    // AE (region 0): [4096][512], row r: m=(r&2047)+1, sin if r<2048; tau=2(j+1)
    // AO (region 1): tau=2j+1
    int r = idx >> 6, j8 = (idx & 63) << 3;
    int m = (r & 2047) + 1;
    bool is_sin = (r < 2048);
    int ph = (region == 0) ? ((m * (2 * j8 + 2)) & 8191) : ((m * (2 * j8 + 1)) & 8191);
    int step = (2 * m) & 8191;
#pragma unroll
    for (int j = 0; j < 8; ++j) {
      float x = ph * C_2PI_8192;
      float v = is_sin ? __sinf(x) : __cosf(x);
      if (j < 4) lo[j] = bf16bits(v); else hi[j - 4] = bf16bits(v);
      ph = (ph + step) & 8191;
    }
    short* dst = (short*)AE + (size_t)region * 2097152 + ((size_t)r << 9) + j8;
    *(short4v*)dst = lo;
    *(short4v*)(dst + 4) = hi;
  } else {
    // Be (region 2): [512][4096], row j: tau=2j+2; Bo (region 3): tau=2j+1
    int jr = idx >> 9, k8 = (idx & 511) << 3;
    int tau = (region == 2) ? (2 * jr + 2) : (2 * jr + 1);
    int m0 = (k8 & 2047) + 1;
    bool is_sin = (k8 < 2048);
    int ph = (m0 * tau) & 8191;
#pragma unroll
    for (int j = 0; j < 8; ++j) {
      float x = ph * C_2PI_8192;
      float v = is_sin ? __sinf(x) : __cosf(x);
      if (j < 4) lo[j] = bf16bits(v); else hi[j - 4] = bf16bits(v);
      ph = (ph + tau) & 8191;
    }
    short* dst = (short*)Be + (size_t)(region - 2) * 2097152 + ((size_t)jr << 12) + k8;
    *(short4v*)dst = lo;
    *(short4v*)(dst + 4) = hi;
  }
}

// ---------------- K3: tau/scal for m in [1,2048] (bid<2048); per-bc prep ------
__global__ __launch_bounds__(256) void k_mid(const float* __restrict__ wt,
                                             const float* __restrict__ nobs,
                                             const float* __restrict__ data,
                                             const float* __restrict__ delta,
                                             const float* __restrict__ invA,
                                             float4* __restrict__ scal,
                                             bf16* __restrict__ dmE,
                                             float* __restrict__ sdv,
                                             float* __restrict__ sd2v,
                                             float* __restrict__ ss4095,
                                             float* __restrict__ cs4096) {
  int bid = blockIdx.x, tid = threadIdx.x;
  int wid = tid >> 6, lane = tid & 63;
  if (bid < 2048) {
    int gw = bid * 4 + wid;          // b*2048 + f, f in [0,2048)
    int b = gw >> 11, f = gw & 2047;
    float num = 0.f, den = 0.f;
    int f2 = 2 * (f + 1);
    for (int t = lane; t < 1024; t += 64) {
      float w = wt[(b << 10) + t];
      int ph = (f2 * (t + 1)) & 8191;
      float x = ph * C_2PI_8192;
      num += w * __sinf(x);
      den += w * __cosf(x);
    }
#pragma unroll
    for (int m = 32; m; m >>= 1) {
      num += __shfl_xor(num, m, 64);
      den += __shfl_xor(den, m, 64);
    }
    if (lane == 0) {
      float th = 0.5f * atan2f(num, den);
      float c = cosf(th), s = sinf(th);
      float nb = nobs[b];
      float WSS = 0.5f * (nb - den);
      float WCC = 0.5f * (nb + den);
      float WSC = 0.5f * num;
      float den_s = c * c * WSS - 2.f * c * s * WSC + s * s * WCC;
      float den_c = c * c * WCC + 2.f * c * s * WSC + s * s * WSS;
      scal[gw] = make_float4(c, s, 1.f / den_s, 1.f / den_c);
    }
  } else {
    int bc = bid - 2048, b = bc >> 9;
    bf16* dmO = dmE + (1 << 20);
    size_t base = (size_t)bc * 1024 + tid * 4;
    float4 d4 = *(const float4*)(data + base);
    float4 w4 = *(const float4*)(wt + (b << 10) + tid * 4);
    float4 e4 = *(const float4*)(delta + (b << 10) + tid * 4);
    const float* d = (const float*)&d4;
    const float* w = (const float*)&w4;
    const float* e = (const float*)&e4;
    float wd[4];
    float sd = 0.f, sd2 = 0.f, sdd = 0.f, sdc = 0.f;
#pragma unroll
    for (int j = 0; j < 4; ++j) {
      wd[j] = w[j] * d[j];
      sd += wd[j];
      sd2 += wd[j] * d[j];
      sdd += wd[j] * e[j];
      sdc += (j & 1) ? wd[j] : -wd[j];  // (-1)^(t+1), t=tid*4+j
    }
    // t even -> tau odd -> dmO[t/2]; t odd -> tau even -> dmE[(t-1)/2]
    short2v dE, dO;
    dO[0] = bf16bits(wd[0]); dE[0] = bf16bits(wd[1]);
    dO[1] = bf16bits(wd[2]); dE[1] = bf16bits(wd[3]);
    *(short2v*)((short*)dmE + (size_t)bc * 512 + tid * 2) = dE;
    *(short2v*)((short*)dmO + (size_t)bc * 512 + tid * 2) = dO;
#pragma unroll
    for (int m = 32; m; m >>= 1) {
      sd += __shfl_xor(sd, m, 64);
      sd2 += __shfl_xor(sd2, m, 64);
      sdd += __shfl_xor(sdd, m, 64);
      sdc += __shfl_xor(sdc, m, 64);
    }
    __shared__ float red[4][4];
    if (lane == 0) { red[wid][0] = sd; red[wid][1] = sd2; red[wid][2] = sdd; red[wid][3] = sdc; }
    __syncthreads();
    if (tid == 0) {
      float a0 = 0, a1 = 0, a2 = 0, a3 = 0;
#pragma unroll
      for (int ww = 0; ww < 4; ++ww) { a0 += red[ww][0]; a1 += red[ww][1]; a2 += red[ww][2]; a3 += red[ww][3]; }
      sdv[bc] = a0;
      sd2v[bc] = a1;
      ss4095[bc] = a2 * invA[b];
      cs4096[bc] = a3 / nobs[b];
    }
  }
}

// ---------------- GEMM1 dual (U=even-tau, V=odd-tau) + butterfly-PQ epilogue --
__global__ __launch_bounds__(256, 2) void k_gemm1_pq(const bf16* __restrict__ dmE,
                                                     const bf16* __restrict__ AE,
                                                     const float4* __restrict__ scal,
                                                     bf16* __restrict__ PQe,
                                                     bf16* __restrict__ PQo) {
  __shared__ bf16 As[128 * 64];
  __shared__ bf16 Bs[128 * 64];
  int bid = blockIdx.x;
  int swz = ((bid & 7) << 6) | (bid >> 3);  // 512 blocks, bijective
  int mt = swz & 15, ft = swz >> 4;          // ft in [0,32)
  int m0 = mt << 7, f0 = ft << 6;
  int tid = threadIdx.x, lane = tid & 63, wid = tid >> 6;
  int wm = (wid >> 1) << 6, wn = (wid & 1) << 6;
  int fr = lane & 15, kh = lane >> 4;

  int r0 = tid >> 3;
  int scol = ((tid & 7) ^ (r0 & 7)) << 3;
  const bf16* pa0 = dmE + (size_t)(m0 + r0) * 512 + scol;
  const bf16* pb[4];
#pragma unroll
  for (int n = 0; n < 4; ++n) {
    int row = n * 32 + r0;
    int gr = ((row >> 4) & 1) * 2048 + f0 + (row & 15) + ((row >> 5) << 4);
    pb[n] = AE + (size_t)gr * 512 + scol;
  }
  char* lA = (char*)As + (wid << 10);
  char* lB = (char*)Bs + (wid << 10);

  f32x4 accU[4][4] = {};
  f32x4 accV[4][4] = {};
  int sw = fr & 7;

#define K_BODY(ACC)                                                              \
  for (int kt = 0; kt < 8; ++kt) {                                               \
    _Pragma("unroll")                                                            \
    for (int n = 0; n < 4; ++n) {                                                \
      GLOAD(pa0 + n * 16384, lA + n * 4096);                                     \
      GLOAD(pb[n], lB + n * 4096);                                               \
      pb[n] += 64;                                                               \
    }                                                                            \
    pa0 += 64;                                                                   \
    __syncthreads();                                                             \
    _Pragma("unroll")                                                            \
    for (int s = 0; s < 2; ++s) {                                                \
      bf16x8 a[4];                                                               \
      _Pragma("unroll")                                                          \
      for (int i = 0; i < 4; ++i)                                                \
        a[i] = *(const bf16x8*)&As[(wm + i * 16 + fr) * 64 + ((((s << 2) + kh) ^ sw) << 3)]; \
      _Pragma("unroll")                                                          \
      for (int j = 0; j < 4; ++j) {                                              \
        bf16x8 bb = *(const bf16x8*)&Bs[(wn + j * 16 + fr) * 64 + ((((s << 2) + kh) ^ sw) << 3)]; \
        _Pragma("unroll")                                                        \
        for (int i = 0; i < 4; ++i)                                              \
          ACC[i][j] = __builtin_amdgcn_mfma_f32_16x16x32_bf16(a[i], bb, ACC[i][j], 0, 0, 0); \
      }                                                                          \
    }                                                                            \
    __syncthreads();                                                             \
  }

  K_BODY(accU)
  pa0 += (1 << 20) - 512;                    // dmO = dmE + 1M elems
#pragma unroll
  for (int n = 0; n < 4; ++n) pb[n] += (2 << 20) - 512;  // AO = AE + 2M elems
  K_BODY(accV)
#undef K_BODY

  int b = m0 >> 9;
  short* pqe = (short*)PQe;
  short* pqo = (short*)PQo;
#pragma unroll
  for (int p = 0; p < 2; ++p) {
    int mi = f0 + (wn >> 1) + (p << 4) + fr;
    float4 sc = scal[(b << 11) + mi];
    float c = sc.x, s = sc.y, ids = sc.z, idc = sc.w;
    bool self = (mi == 2047);  // m=2048 pairs with itself: no partner term
#pragma unroll
    for (int i = 0; i < 4; ++i) {
#pragma unroll
      for (int q = 0; q < 4; ++q) {
        int bc = m0 + wm + i * 16 + (kh << 2) + q;
        float US = accU[i][2 * p][q], UC = accU[i][2 * p + 1][q];
        float VS = accV[i][2 * p][q], VC = accV[i][2 * p + 1][q];
        float Gs = US + VS, Gc = UC + VC;      // freq m
        float gs = VS - US, gc = UC - VC;      // freq 4096-m
        float ss = (c * Gs - s * Gc) * ids;
        float cs = (c * Gc + s * Gs) * idc;
        float P = c * ss + s * cs;
        float Q = c * cs - s * ss;
        float ssp = (c * gs + s * gc) * ids;   // partner scal: (c,-s,ids,idc)
        float csp = (c * gc - s * gs) * idc;
        float Pp = self ? 0.f : (c * ssp - s * csp);
        float Qp = self ? 0.f : (c * csp + s * ssp);
        size_t base = (size_t)bc * 4096 + mi;
        pqe[base] = bf16bits(P - Pp);
        pqe[base + 2048] = bf16bits(Q + Qp);
        pqo[base] = bf16bits(P + Pp);
        pqo[base + 2048] = bf16bits(Q - Qp);
      }
    }
  }
}

// ---------------- GEMM2 (NT, eo x split-K=8, fp16 partials) -------------------
__global__ __launch_bounds__(256, 4) void k_gemm2(const bf16* __restrict__ PQe,
                                                  const bf16* __restrict__ Be,
                                                  _Float16* __restrict__ Pe) {
  __shared__ bf16 As[128 * 64];
  __shared__ bf16 Bs[128 * 64];
  int bid = blockIdx.x;
  int swz = ((bid & 7) << 7) | (bid >> 3);  // 1024 blocks, bijective
  int eo = swz >> 9;
  int slice = (swz >> 6) & 7;
  int tl = swz & 63;
  int mt = tl & 15, nt = tl >> 4;
  int m0 = mt << 7, n0 = nt << 7;
  int tid = threadIdx.x, lane = tid & 63, wid = tid >> 6;
  int wm = (wid >> 1) << 6, wn = (wid & 1) << 6;
  int fr = lane & 15, kh = lane >> 4;

  const bf16* A = PQe + (size_t)eo * (8 << 20);
  const bf16* B = Be + (size_t)eo * (2 << 20);
  _Float16* C = Pe + (size_t)eo * (8 << 20);

  int r0 = tid >> 3;
  int scol = ((tid & 7) ^ (r0 & 7)) << 3;
  const bf16* pa0 = A + (size_t)slice * 512 + (size_t)(m0 + r0) * 4096 + scol;
  const bf16* pb0 = B + (size_t)slice * 512 + (size_t)(n0 + r0) * 4096 + scol;
  _Float16* Cp = C + (size_t)slice * 1048576;
  char* lA = (char*)As + (wid << 10);
  char* lB = (char*)Bs + (wid << 10);

  f32x4 acc[4][4] = {};
  int sw = fr & 7;

  for (int kt = 0; kt < 8; ++kt) {
#pragma unroll
    for (int n = 0; n < 4; ++n) {
      GLOAD(pa0 + n * 131072, lA + n * 4096);
      GLOAD(pb0 + n * 131072, lB + n * 4096);
    }
    pa0 += 64; pb0 += 64;
    __syncthreads();
#pragma unroll
    for (int s = 0; s < 2; ++s) {
      bf16x8 a[4];
#pragma unroll
      for (int i = 0; i < 4; ++i)
        a[i] = *(const bf16x8*)&As[(wm + i * 16 + fr) * 64 + ((((s << 2) + kh) ^ sw) << 3)];
#pragma unroll
      for (int j = 0; j < 4; ++j) {
        bf16x8 bb = *(const bf16x8*)&Bs[(wn + j * 16 + fr) * 64 + ((((s << 2) + kh) ^ sw) << 3)];
#pragma unroll
        for (int i = 0; i < 4; ++i)
          acc[i][j] = __builtin_amdgcn_mfma_f32_16x16x32_bf16(a[i], bb, acc[i][j], 0, 0, 0);
      }
    }
    __syncthreads();
  }
#pragma unroll
  for (int i = 0; i < 4; ++i) {
#pragma unroll
    for (int q = 0; q < 4; ++q) {
      size_t row = m0 + wm + i * 16 + (kh << 2) + q;
      _Float16* cp = Cp + row * 512 + n0 + wn + fr;
#pragma unroll
      for (int j = 0; j < 4; ++j) cp[j * 16] = (_Float16)acc[i][j][q];
    }
  }
}

// ---------------- K-tail: merge Re/Ro slices + fixups + stats + final select --
__global__ __launch_bounds__(256) void k_tail(const _Float16* __restrict__ Pe,
                                              const _Float16* __restrict__ Po,
                                              const float* __restrict__ data,
                                              const float* __restrict__ wt,
                                              const float* __restrict__ delta,
                                              const float* __restrict__ ss4095,
                                              const float* __restrict__ cs4096,
                                              const float* __restrict__ sdv,
                                              const float* __restrict__ sd2v,
                                              const float* __restrict__ nobs,
                                              float* __restrict__ out) {
  int bc = blockIdx.x, b = bc >> 9, tid = threadIdx.x;
  size_t base = (size_t)bc * 1024 + tid * 4;
  int jj = tid * 2;
  float r[4] = {0.f, 0.f, 0.f, 0.f};
#pragma unroll
  for (int s = 0; s < 8; ++s) {
    halfx2 pe = *(const halfx2*)(Pe + (size_t)s * 1048576 + (size_t)bc * 512 + jj);
    halfx2 po = *(const halfx2*)(Po + (size_t)s * 1048576 + (size_t)bc * 512 + jj);
    r[0] += (float)po[0];  // t even -> tau odd -> Ro
    r[1] += (float)pe[0];  // t odd  -> tau even -> Re
    r[2] += (float)po[1];
    r[3] += (float)pe[1];
  }
  float ssv = ss4095[bc], csv = cs4096[bc];
  float4 e4 = *(const float4*)(delta + (b << 10) + tid * 4);
  float4 w4 = *(const float4*)(wt + (b << 10) + tid * 4);
  float4 d4 = *(const float4*)(data + base);
  const float* e = (const float*)&e4;
  const float* w = (const float*)&w4;
  const float* d = (const float*)&d4;
  float sr = 0.f, sr2 = 0.f;
#pragma unroll
  for (int j = 0; j < 4; ++j) {
    r[j] += e[j] * ssv + ((j & 1) ? csv : -csv);  // sin4095 + cos4096 fixups
    float wr = w[j] * r[j];
    sr += wr;
    sr2 += wr * r[j];
  }
#pragma unroll
  for (int m = 32; m; m >>= 1) {
    sr += __shfl_xor(sr, m, 64);
    sr2 += __shfl_xor(sr2, m, 64);
  }
  __shared__ float red[4][2];
  __shared__ float s_inv;
  int wid = tid >> 6, lane = tid & 63;
  if (lane == 0) { red[wid][0] = sr; red[wid][1] = sr2; }
  __syncthreads();
  if (tid == 0) {
    float a0 = 0, a1 = 0;
#pragma unroll
    for (int ww = 0; ww < 4; ++ww) { a0 += red[ww][0]; a1 += red[ww][1]; }
    float n = nobs[b];
    float mr = a0 / n, vr = (a1 - n * mr * mr) / (n - 1.f);
    float md = sdv[bc] / n, vd = (sd2v[bc] - n * md * md) / (n - 1.f);
    s_inv = sqrtf(vd / vr);
  }
  __syncthreads();
  float inv = s_inv;
  float4 o;
  ((float*)&o)[0] = (w[0] != 0.f) ? d[0] : r[0] * inv;
  ((float*)&o)[1] = (w[1] != 0.f) ? d[1] : r[1] * inv;
  ((float*)&o)[2] = (w[2] != 0.f) ? d[2] : r[2] * inv;
  ((float*)&o)[3] = (w[3] != 0.f) ? d[3] : r[3] * inv;
  *(float4*)(out + base) = o;
}

extern "C" void kernel_launch(void* const* d_in, const int* in_sizes, int n_in,
                              void* d_out, int out_size, void* d_ws, size_t ws_size,
                              hipStream_t stream) {
  const float* data = (const float*)d_in[0];
  const void* mask = d_in[1];
  float* out = (float*)d_out;
  char* ws = (char*)d_ws;

  float* wt = (float*)(ws);                  // 16 KB
  float* nobs = (float*)(ws + 16384);
  float* invA = (float*)(ws + 16640);
  float* sdv = (float*)(ws + 17408);         // 8 KB
  float* sd2v = (float*)(ws + 25600);        // 8 KB
  float* ss4095 = (float*)(ws + 33792);      // 8 KB
  float* cs4096 = (float*)(ws + 41984);      // 8 KB
  float* delta = (float*)(ws + 50176);       // 16 KB
  float4* scal = (float4*)(ws + 131072);     // 128 KB
  const size_t MB = 1ull << 20;
  bf16* AE = (bf16*)(ws + 1 * MB);           // AE 4MB @1MB, AO 4MB @5MB (contig)
  bf16* Be = (bf16*)(ws + 9 * MB);           // Be 4MB @9MB, Bo 4MB @13MB (contig)
  bf16* dmE = (bf16*)(ws + 17 * MB);         // dmE 2MB @17MB, dmO 2MB @19MB
  bf16* PQe = (bf16*)(ws + 21 * MB);         // 16MB @21MB
  bf16* PQo = (bf16*)(ws + 37 * MB);         // 16MB @37MB (PQe+8M elems)
  _Float16* Pe = (_Float16*)(ws + 53 * MB);  // 16MB @53MB
  _Float16* Po = (_Float16*)(ws + 69 * MB);  // 16MB @69MB (Pe+8M elems)

  k_prep<<<1, 1024, 0, stream>>>(mask, wt, nobs, delta, invA);
  k_build<<<4096, 256, 0, stream>>>(AE, Be);
  k_mid<<<4096, 256, 0, stream>>>(wt, nobs, data, delta, invA, scal, dmE, sdv, sd2v, ss4095, cs4096);
  // GEMM1 dual: U,V (M=2048,N=4096,K=512 each), butterfly+PQ fused epilogue
  k_gemm1_pq<<<512, 256, 0, stream>>>(dmE, AE, scal, PQe, PQo);
  // GEMM2: Re/Ro (M=2048,N=512,K=4096) x2, split-K=8, fp16 partials
  k_gemm2<<<1024, 256, 0, stream>>>(PQe, Be, Pe);
  k_tail<<<2048, 256, 0, stream>>>(Pe, Po, data, wt, delta, ss4095, cs4096, sdv, sd2v, nobs, out);
}

// Round 7
// 94.358 us; speedup vs baseline: 3.4773x; 1.0836x over previous
//
#include <hip/hip_runtime.h>
#include <hip/hip_bf16.h>
#include <hip/hip_fp16.h>

using bf16 = __hip_bfloat16;
typedef __attribute__((ext_vector_type(8))) short bf16x8;
typedef __attribute__((ext_vector_type(4))) short short4v;
typedef __attribute__((ext_vector_type(2))) short short2v;
typedef __attribute__((ext_vector_type(4))) float f32x4;
typedef __attribute__((ext_vector_type(2))) _Float16 halfx2;

#define C_2PI_8192 7.6699039394282072e-4f

static __device__ __forceinline__ short bf16bits(float v) {
  bf16 h = __float2bfloat16(v);
  return *reinterpret_cast<short*>(&h);
}

#define GLOAD(gp, lp)                                                          \
  __builtin_amdgcn_global_load_lds(                                            \
      (const __attribute__((address_space(1))) void*)(gp),                     \
      (__attribute__((address_space(3))) void*)(lp), 16, 0, 0)

// ---------------- K1: mask detect + wt + nobs + f=4095 sin f32-replica fixup --
// (reference-replica path: accurate sinf/cosf REQUIRED, do not use fast trig)
__global__ __launch_bounds__(1024) void k_prep(const void* __restrict__ mask,
                                               float* __restrict__ wt,
                                               float* __restrict__ nobs,
                                               float* __restrict__ delta,
                                               float* __restrict__ invA) {
  __shared__ int cnt;
  __shared__ float wsum[16];
  int tid = threadIdx.x;
  if (tid == 0) cnt = 0;
  __syncthreads();
  const unsigned char* mb = (const unsigned char*)mask;
  int c = 0;
#pragma unroll
  for (int i = 0; i < 4; ++i) c += (mb[tid * 4 + i] != 0) ? 1 : 0;
  atomicAdd(&cnt, c);
  __syncthreads();
  bool bytemode = (cnt > 2048);
  const int* mi = (const int*)mask;
  float s = 0.f;
#pragma unroll
  for (int i = 0; i < 4; ++i) {
    int e = tid * 4 + i;
    bool on = bytemode ? (mb[e] != 0) : (mi[e] != 0);
    float w = on ? 1.0f : 0.0f;
    wt[e] = w;
    s += w;
  }
#pragma unroll
  for (int m = 32; m; m >>= 1) s += __shfl_xor(s, m, 64);
  int wid = tid >> 6, lane = tid & 63;
  if (lane == 0) wsum[wid] = s;
  __syncthreads();
  if (tid < 4) nobs[tid] = wsum[tid * 4] + wsum[tid * 4 + 1] + wsum[tid * 4 + 2] + wsum[tid * 4 + 3];
  __syncthreads();
  if (tid < 256) {
    const float W = (float)(6.283185307179586 / 8192.0);
    const float ang = W * 4096.0f;
    int b = tid >> 6;
    const float* wp = wt + (b << 10);
    float num = 0.f, den = 0.f;
    for (int t = lane; t < 1024; t += 64) {
      float tf = (float)(t + 1);
      float arg = ang * tf;
      float w = wp[t];
      num += w * sinf(2.0f * arg);
      den += w * cosf(2.0f * arg);
    }
#pragma unroll
    for (int m = 32; m; m >>= 1) {
      num += __shfl_xor(num, m, 64);
      den += __shfl_xor(den, m, 64);
    }
    float tau = atan2f(num, den) / (2.0f * ang);
    float P = ang * tau;
    float dss = 0.f;
    for (int t = lane; t < 1024; t += 64) {
      float tf = (float)(t + 1);
      float arg = ang * tf;
      float d = sinf(arg - P);
      delta[(b << 10) + t] = d;
      dss += wp[t] * d * d;
    }
#pragma unroll
    for (int m = 32; m; m >>= 1) dss += __shfl_xor(dss, m, 64);
    if (lane == 0) invA[b] = 1.f / dss;
  }
}

// ---------------- K2: basis tables (rotation recurrence: 2 trans + 7 rot) -----
__global__ void k_build(bf16* __restrict__ AE, bf16* __restrict__ Be) {
  int bid = blockIdx.x;
  int region = bid >> 10;
  int idx = (bid & 1023) * 256 + threadIdx.x;
  short4v lo, hi;
  if (region < 2) {
    // AE (region 0): [4096][512], row r: m=(r&2047)+1, sin if r<2048; tau=2(j+1)
    // AO (region 1): tau=2j+1
    int r = idx >> 6, j8 = (idx & 63) << 3;
    int m = (r & 2047) + 1;
    bool is_sin = (r < 2048);
    int ph0 = (region == 0) ? ((m * (2 * j8 + 2)) & 8191) : ((m * (2 * j8 + 1)) & 8191);
    int step = (2 * m) & 8191;
    float s = __sinf(ph0 * C_2PI_8192), c = __cosf(ph0 * C_2PI_8192);
    float sr = __sinf(step * C_2PI_8192), cr = __cosf(step * C_2PI_8192);
#pragma unroll
    for (int j = 0; j < 8; ++j) {
      float v = is_sin ? s : c;
      if (j < 4) lo[j] = bf16bits(v); else hi[j - 4] = bf16bits(v);
      float ns = s * cr + c * sr;
      c = c * cr - s * sr;
      s = ns;
    }
    short* dst = (short*)AE + (size_t)region * 2097152 + ((size_t)r << 9) + j8;
    *(short4v*)dst = lo;
    *(short4v*)(dst + 4) = hi;
  } else {
    // Be (region 2): [512][4096], row j: tau=2j+2; Bo (region 3): tau=2j+1
    int jr = idx >> 9, k8 = (idx & 511) << 3;
    int tau = (region == 2) ? (2 * jr + 2) : (2 * jr + 1);
    int m0 = (k8 & 2047) + 1;
    bool is_sin = (k8 < 2048);
    int ph0 = (m0 * tau) & 8191;
    float s = __sinf(ph0 * C_2PI_8192), c = __cosf(ph0 * C_2PI_8192);
    float sr = __sinf(tau * C_2PI_8192), cr = __cosf(tau * C_2PI_8192);
#pragma unroll
    for (int j = 0; j < 8; ++j) {
      float v = is_sin ? s : c;
      if (j < 4) lo[j] = bf16bits(v); else hi[j - 4] = bf16bits(v);
      float ns = s * cr + c * sr;
      c = c * cr - s * sr;
      s = ns;
    }
    short* dst = (short*)Be + (size_t)(region - 2) * 2097152 + ((size_t)jr << 12) + k8;
    *(short4v*)dst = lo;
    *(short4v*)(dst + 4) = hi;
  }
}

// ---------------- K3: tau/scal for m in [1,2048] (bid<2048); per-bc prep ------
__global__ __launch_bounds__(256) void k_mid(const float* __restrict__ wt,
                                             const float* __restrict__ nobs,
                                             const float* __restrict__ data,
                                             const float* __restrict__ delta,
                                             const float* __restrict__ invA,
                                             float4* __restrict__ scal,
                                             bf16* __restrict__ dmE,
                                             float* __restrict__ sdv,
                                             float* __restrict__ sd2v,
                                             float* __restrict__ ss4095,
                                             float* __restrict__ cs4096) {
  int bid = blockIdx.x, tid = threadIdx.x;
  int wid = tid >> 6, lane = tid & 63;
  if (bid < 2048) {
    int gw = bid * 4 + wid;          // b*2048 + f, f in [0,2048)
    int b = gw >> 11, f = gw & 2047;
    float num = 0.f, den = 0.f;
    int f2 = 2 * (f + 1);
    // rotation recurrence: phase step per t-stride(64) is constant
    {
      int ph0 = (f2 * (lane + 1)) & 8191;
      int st = (f2 << 6) & 8191;
      float s = __sinf(ph0 * C_2PI_8192), c = __cosf(ph0 * C_2PI_8192);
      float sr = __sinf(st * C_2PI_8192), cr = __cosf(st * C_2PI_8192);
      const float* wp = wt + (b << 10) + lane;
#pragma unroll
      for (int i = 0; i < 16; ++i) {
        float w = wp[i << 6];
        num += w * s;
        den += w * c;
        float ns = s * cr + c * sr;
        c = c * cr - s * sr;
        s = ns;
      }
    }
#pragma unroll
    for (int m = 32; m; m >>= 1) {
      num += __shfl_xor(num, m, 64);
      den += __shfl_xor(den, m, 64);
    }
    if (lane == 0) {
      float th = 0.5f * atan2f(num, den);
      float c = cosf(th), s = sinf(th);
      float nb = nobs[b];
      float WSS = 0.5f * (nb - den);
      float WCC = 0.5f * (nb + den);
      float WSC = 0.5f * num;
      float den_s = c * c * WSS - 2.f * c * s * WSC + s * s * WCC;
      float den_c = c * c * WCC + 2.f * c * s * WSC + s * s * WSS;
      scal[gw] = make_float4(c, s, 1.f / den_s, 1.f / den_c);
    }
  } else {
    int bc = bid - 2048, b = bc >> 9;
    bf16* dmO = dmE + (1 << 20);
    size_t base = (size_t)bc * 1024 + tid * 4;
    float4 d4 = *(const float4*)(data + base);
    float4 w4 = *(const float4*)(wt + (b << 10) + tid * 4);
    float4 e4 = *(const float4*)(delta + (b << 10) + tid * 4);
    const float* d = (const float*)&d4;
    const float* w = (const float*)&w4;
    const float* e = (const float*)&e4;
    float wd[4];
    float sd = 0.f, sd2 = 0.f, sdd = 0.f, sdc = 0.f;
#pragma unroll
    for (int j = 0; j < 4; ++j) {
      wd[j] = w[j] * d[j];
      sd += wd[j];
      sd2 += wd[j] * d[j];
      sdd += wd[j] * e[j];
      sdc += (j & 1) ? wd[j] : -wd[j];  // (-1)^(t+1), t=tid*4+j
    }
    // t even -> tau odd -> dmO[t/2]; t odd -> tau even -> dmE[(t-1)/2]
    short2v dE, dO;
    dO[0] = bf16bits(wd[0]); dE[0] = bf16bits(wd[1]);
    dO[1] = bf16bits(wd[2]); dE[1] = bf16bits(wd[3]);
    *(short2v*)((short*)dmE + (size_t)bc * 512 + tid * 2) = dE;
    *(short2v*)((short*)dmO + (size_t)bc * 512 + tid * 2) = dO;
#pragma unroll
    for (int m = 32; m; m >>= 1) {
      sd += __shfl_xor(sd, m, 64);
      sd2 += __shfl_xor(sd2, m, 64);
      sdd += __shfl_xor(sdd, m, 64);
      sdc += __shfl_xor(sdc, m, 64);
    }
    __shared__ float red[4][4];
    if (lane == 0) { red[wid][0] = sd; red[wid][1] = sd2; red[wid][2] = sdd; red[wid][3] = sdc; }
    __syncthreads();
    if (tid == 0) {
      float a0 = 0, a1 = 0, a2 = 0, a3 = 0;
#pragma unroll
      for (int ww = 0; ww < 4; ++ww) { a0 += red[ww][0]; a1 += red[ww][1]; a2 += red[ww][2]; a3 += red[ww][3]; }
      sdv[bc] = a0;
      sd2v[bc] = a1;
      ss4095[bc] = a2 * invA[b];
      cs4096[bc] = a3 / nobs[b];
    }
  }
}

// ---------------- GEMM1 dual (U=even-tau, V=odd-tau) + butterfly-PQ epilogue --
__global__ __launch_bounds__(256, 2) void k_gemm1_pq(const bf16* __restrict__ dmE,
                                                     const bf16* __restrict__ AE,
                                                     const float4* __restrict__ scal,
                                                     bf16* __restrict__ PQe,
                                                     bf16* __restrict__ PQo) {
  __shared__ bf16 As[128 * 64];
  __shared__ bf16 Bs[128 * 64];
  int bid = blockIdx.x;
  int swz = ((bid & 7) << 6) | (bid >> 3);  // 512 blocks, bijective
  int mt = swz & 15, ft = swz >> 4;          // ft in [0,32)
  int m0 = mt << 7, f0 = ft << 6;
  int tid = threadIdx.x, lane = tid & 63, wid = tid >> 6;
  int wm = (wid >> 1) << 6, wn = (wid & 1) << 6;
  int fr = lane & 15, kh = lane >> 4;

  int r0 = tid >> 3;
  int scol = ((tid & 7) ^ (r0 & 7)) << 3;
  const bf16* pa0 = dmE + (size_t)(m0 + r0) * 512 + scol;
  const bf16* pb[4];
#pragma unroll
  for (int n = 0; n < 4; ++n) {
    int row = n * 32 + r0;
    int gr = ((row >> 4) & 1) * 2048 + f0 + (row & 15) + ((row >> 5) << 4);
    pb[n] = AE + (size_t)gr * 512 + scol;
  }
  char* lA = (char*)As + (wid << 10);
  char* lB = (char*)Bs + (wid << 10);

  f32x4 accU[4][4] = {};
  f32x4 accV[4][4] = {};
  int sw = fr & 7;

#define K_BODY(ACC)                                                              \
  for (int kt = 0; kt < 8; ++kt) {                                               \
    _Pragma("unroll")                                                            \
    for (int n = 0; n < 4; ++n) {                                                \
      GLOAD(pa0 + n * 16384, lA + n * 4096);                                     \
      GLOAD(pb[n], lB + n * 4096);                                               \
      pb[n] += 64;                                                               \
    }                                                                            \
    pa0 += 64;                                                                   \
    __syncthreads();                                                             \
    _Pragma("unroll")                                                            \
    for (int s = 0; s < 2; ++s) {                                                \
      bf16x8 a[4];                                                               \
      _Pragma("unroll")                                                          \
      for (int i = 0; i < 4; ++i)                                                \
        a[i] = *(const bf16x8*)&As[(wm + i * 16 + fr) * 64 + ((((s << 2) + kh) ^ sw) << 3)]; \
      _Pragma("unroll")                                                          \
      for (int j = 0; j < 4; ++j) {                                              \
        bf16x8 bb = *(const bf16x8*)&Bs[(wn + j * 16 + fr) * 64 + ((((s << 2) + kh) ^ sw) << 3)]; \
        _Pragma("unroll")                                                        \
        for (int i = 0; i < 4; ++i)                                              \
          ACC[i][j] = __builtin_amdgcn_mfma_f32_16x16x32_bf16(a[i], bb, ACC[i][j], 0, 0, 0); \
      }                                                                          \
    }                                                                            \
    __syncthreads();                                                             \
  }

  K_BODY(accU)
  pa0 += (1 << 20) - 512;                    // dmO = dmE + 1M elems
#pragma unroll
  for (int n = 0; n < 4; ++n) pb[n] += (2 << 20) - 512;  // AO = AE + 2M elems
  K_BODY(accV)
#undef K_BODY

  int b = m0 >> 9;
  short* pqe = (short*)PQe;
  short* pqo = (short*)PQo;
#pragma unroll
  for (int p = 0; p < 2; ++p) {
    int mi = f0 + (wn >> 1) + (p << 4) + fr;
    float4 sc = scal[(b << 11) + mi];
    float c = sc.x, s = sc.y, ids = sc.z, idc = sc.w;
    bool self = (mi == 2047);  // m=2048 pairs with itself: no partner term
#pragma unroll
    for (int i = 0; i < 4; ++i) {
#pragma unroll
      for (int q = 0; q < 4; ++q) {
        int bc = m0 + wm + i * 16 + (kh << 2) + q;
        float US = accU[i][2 * p][q], UC = accU[i][2 * p + 1][q];
        float VS = accV[i][2 * p][q], VC = accV[i][2 * p + 1][q];
        float Gs = US + VS, Gc = UC + VC;      // freq m
        float gs = VS - US, gc = UC - VC;      // freq 4096-m
        float ss = (c * Gs - s * Gc) * ids;
        float cs = (c * Gc + s * Gs) * idc;
        float P = c * ss + s * cs;
        float Q = c * cs - s * ss;
        float ssp = (c * gs + s * gc) * ids;   // partner scal: (c,-s,ids,idc)
        float csp = (c * gc - s * gs) * idc;
        float Pp = self ? 0.f : (c * ssp - s * csp);
        float Qp = self ? 0.f : (c * csp + s * ssp);
        size_t base = (size_t)bc * 4096 + mi;
        pqe[base] = bf16bits(P - Pp);
        pqe[base + 2048] = bf16bits(Q + Qp);
        pqo[base] = bf16bits(P + Pp);
        pqo[base + 2048] = bf16bits(Q - Qp);
      }
    }
  }
}

// ---------------- GEMM2 (NT, eo x split-K=4, fp16 partials) -------------------
__global__ __launch_bounds__(256, 4) void k_gemm2(const bf16* __restrict__ PQe,
                                                  const bf16* __restrict__ Be,
                                                  _Float16* __restrict__ Pe) {
  __shared__ bf16 As[128 * 64];
  __shared__ bf16 Bs[128 * 64];
  int bid = blockIdx.x;
  int swz = ((bid & 7) << 6) | (bid >> 3);  // 512 blocks, bijective
  int eo = swz >> 8;
  int slice = (swz >> 6) & 3;
  int tl = swz & 63;
  int mt = tl & 15, nt = tl >> 4;
  int m0 = mt << 7, n0 = nt << 7;
  int tid = threadIdx.x, lane = tid & 63, wid = tid >> 6;
  int wm = (wid >> 1) << 6, wn = (wid & 1) << 6;
  int fr = lane & 15, kh = lane >> 4;

  const bf16* A = PQe + (size_t)eo * (8 << 20);
  const bf16* B = Be + (size_t)eo * (2 << 20);
  _Float16* C = Pe + (size_t)eo * (8 << 20);

  int r0 = tid >> 3;
  int scol = ((tid & 7) ^ (r0 & 7)) << 3;
  const bf16* pa0 = A + (size_t)slice * 1024 + (size_t)(m0 + r0) * 4096 + scol;
  const bf16* pb0 = B + (size_t)slice * 1024 + (size_t)(n0 + r0) * 4096 + scol;
  _Float16* Cp = C + (size_t)slice * 1048576;
  char* lA = (char*)As + (wid << 10);
  char* lB = (char*)Bs + (wid << 10);

  f32x4 acc[4][4] = {};
  int sw = fr & 7;

  for (int kt = 0; kt < 16; ++kt) {
#pragma unroll
    for (int n = 0; n < 4; ++n) {
      GLOAD(pa0 + n * 131072, lA + n * 4096);
      GLOAD(pb0 + n * 131072, lB + n * 4096);
    }
    pa0 += 64; pb0 += 64;
    __syncthreads();
#pragma unroll
    for (int s = 0; s < 2; ++s) {
      bf16x8 a[4];
#pragma unroll
      for (int i = 0; i < 4; ++i)
        a[i] = *(const bf16x8*)&As[(wm + i * 16 + fr) * 64 + ((((s << 2) + kh) ^ sw) << 3)];
#pragma unroll
      for (int j = 0; j < 4; ++j) {
        bf16x8 bb = *(const bf16x8*)&Bs[(wn + j * 16 + fr) * 64 + ((((s << 2) + kh) ^ sw) << 3)];
#pragma unroll
        for (int i = 0; i < 4; ++i)
          acc[i][j] = __builtin_amdgcn_mfma_f32_16x16x32_bf16(a[i], bb, acc[i][j], 0, 0, 0);
      }
    }
    __syncthreads();
  }
#pragma unroll
  for (int i = 0; i < 4; ++i) {
#pragma unroll
    for (int q = 0; q < 4; ++q) {
      size_t row = m0 + wm + i * 16 + (kh << 2) + q;
      _Float16* cp = Cp + row * 512 + n0 + wn + fr;
#pragma unroll
      for (int j = 0; j < 4; ++j) cp[j * 16] = (_Float16)acc[i][j][q];
    }
  }
}

// ---------------- K-tail: merge Re/Ro slices + fixups + stats + final select --
__global__ __launch_bounds__(256) void k_tail(const _Float16* __restrict__ Pe,
                                              const _Float16* __restrict__ Po,
                                              const float* __restrict__ data,
                                              const float* __restrict__ wt,
                                              const float* __restrict__ delta,
                                              const float* __restrict__ ss4095,
                                              const float* __restrict__ cs4096,
                                              const float* __restrict__ sdv,
                                              const float* __restrict__ sd2v,
                                              const float* __restrict__ nobs,
                                              float* __restrict__ out) {
  int bc = blockIdx.x, b = bc >> 9, tid = threadIdx.x;
  size_t base = (size_t)bc * 1024 + tid * 4;
  int jj = tid * 2;
  float r[4] = {0.f, 0.f, 0.f, 0.f};
#pragma unroll
  for (int s = 0; s < 4; ++s) {
    halfx2 pe = *(const halfx2*)(Pe + (size_t)s * 1048576 + (size_t)bc * 512 + jj);
    halfx2 po = *(const halfx2*)(Po + (size_t)s * 1048576 + (size_t)bc * 512 + jj);
    r[0] += (float)po[0];  // t even -> tau odd -> Ro
    r[1] += (float)pe[0];  // t odd  -> tau even -> Re
    r[2] += (float)po[1];
    r[3] += (float)pe[1];
  }
  float ssv = ss4095[bc], csv = cs4096[bc];
  float4 e4 = *(const float4*)(delta + (b << 10) + tid * 4);
  float4 w4 = *(const float4*)(wt + (b << 10) + tid * 4);
  float4 d4 = *(const float4*)(data + base);
  const float* e = (const float*)&e4;
  const float* w = (const float*)&w4;
  const float* d = (const float*)&d4;
  float sr = 0.f, sr2 = 0.f;
#pragma unroll
  for (int j = 0; j < 4; ++j) {
    r[j] += e[j] * ssv + ((j & 1) ? csv : -csv);  // sin4095 + cos4096 fixups
    float wr = w[j] * r[j];
    sr += wr;
    sr2 += wr * r[j];
  }
#pragma unroll
  for (int m = 32; m; m >>= 1) {
    sr += __shfl_xor(sr, m, 64);
    sr2 += __shfl_xor(sr2, m, 64);
  }
  __shared__ float red[4][2];
  __shared__ float s_inv;
  int wid = tid >> 6, lane = tid & 63;
  if (lane == 0) { red[wid][0] = sr; red[wid][1] = sr2; }
  __syncthreads();
  if (tid == 0) {
    float a0 = 0, a1 = 0;
#pragma unroll
    for (int ww = 0; ww < 4; ++ww) { a0 += red[ww][0]; a1 += red[ww][1]; }
    float n = nobs[b];
    float mr = a0 / n, vr = (a1 - n * mr * mr) / (n - 1.f);
    float md = sdv[bc] / n, vd = (sd2v[bc] - n * md * md) / (n - 1.f);
    s_inv = sqrtf(vd / vr);
  }
  __syncthreads();
  float inv = s_inv;
  float4 o;
  ((float*)&o)[0] = (w[0] != 0.f) ? d[0] : r[0] * inv;
  ((float*)&o)[1] = (w[1] != 0.f) ? d[1] : r[1] * inv;
  ((float*)&o)[2] = (w[2] != 0.f) ? d[2] : r[2] * inv;
  ((float*)&o)[3] = (w[3] != 0.f) ? d[3] : r[3] * inv;
  *(float4*)(out + base) = o;
}

extern "C" void kernel_launch(void* const* d_in, const int* in_sizes, int n_in,
                              void* d_out, int out_size, void* d_ws, size_t ws_size,
                              hipStream_t stream) {
  const float* data = (const float*)d_in[0];
  const void* mask = d_in[1];
  float* out = (float*)d_out;
  char* ws = (char*)d_ws;

  float* wt = (float*)(ws);                  // 16 KB
  float* nobs = (float*)(ws + 16384);
  float* invA = (float*)(ws + 16640);
  float* sdv = (float*)(ws + 17408);         // 8 KB
  float* sd2v = (float*)(ws + 25600);        // 8 KB
  float* ss4095 = (float*)(ws + 33792);      // 8 KB
  float* cs4096 = (float*)(ws + 41984);      // 8 KB
  float* delta = (float*)(ws + 50176);       // 16 KB
  float4* scal = (float4*)(ws + 131072);     // 128 KB
  const size_t MB = 1ull << 20;
  bf16* AE = (bf16*)(ws + 1 * MB);           // AE 4MB @1MB, AO 4MB @5MB (contig)
  bf16* Be = (bf16*)(ws + 9 * MB);           // Be 4MB @9MB, Bo 4MB @13MB (contig)
  bf16* dmE = (bf16*)(ws + 17 * MB);         // dmE 2MB @17MB, dmO 2MB @19MB
  bf16* PQe = (bf16*)(ws + 21 * MB);         // 16MB @21MB
  bf16* PQo = (bf16*)(ws + 37 * MB);         // 16MB @37MB (PQe+8M elems)
  _Float16* Pe = (_Float16*)(ws + 53 * MB);  // 8MB used @53MB (stride to Po = 8M elems)
  _Float16* Po = (_Float16*)(ws + 69 * MB);  // 8MB used @69MB

  k_prep<<<1, 1024, 0, stream>>>(mask, wt, nobs, delta, invA);
  k_build<<<4096, 256, 0, stream>>>(AE, Be);
  k_mid<<<4096, 256, 0, stream>>>(wt, nobs, data, delta, invA, scal, dmE, sdv, sd2v, ss4095, cs4096);
  // GEMM1 dual: U,V (M=2048,N=4096,K=512 each), butterfly+PQ fused epilogue
  k_gemm1_pq<<<512, 256, 0, stream>>>(dmE, AE, scal, PQe, PQo);
  // GEMM2: Re/Ro (M=2048,N=512,K=4096) x2, split-K=4, fp16 partials
  k_gemm2<<<512, 256, 0, stream>>>(PQe, Be, Pe);
  k_tail<<<2048, 256, 0, stream>>>(Pe, Po, data, wt, delta, ss4095, cs4096, sdv, sd2v, nobs, out);
}

// Round 8
// 87.603 us; speedup vs baseline: 3.7455x; 1.0771x over previous
//
#include <hip/hip_runtime.h>
#include <hip/hip_bf16.h>
#include <hip/hip_fp16.h>

using bf16 = __hip_bfloat16;
typedef __attribute__((ext_vector_type(8))) short bf16x8;
typedef __attribute__((ext_vector_type(4))) short short4v;
typedef __attribute__((ext_vector_type(2))) short short2v;
typedef __attribute__((ext_vector_type(4))) float f32x4;
typedef __attribute__((ext_vector_type(2))) _Float16 halfx2;

#define C_2PI_8192 7.6699039394282072e-4f

static __device__ __forceinline__ short bf16bits(float v) {
  bf16 h = __float2bfloat16(v);
  return *reinterpret_cast<short*>(&h);
}

#define GLOAD(gp, lp)                                                          \
  __builtin_amdgcn_global_load_lds(                                            \
      (const __attribute__((address_space(1))) void*)(gp),                     \
      (__attribute__((address_space(3))) void*)(lp), 16, 0, 0)

// Decentralized mask-mode detect: 256 threads count nonzero bytes in mask[0:4096).
// byte-bools ~75% nonzero; int32-bools ~18.75%. Threshold 50%. Deterministic and
// identical across all blocks (same bytes, same logic).
#define DETECT_BYTEMODE(mask, tid, outvar)                                     \
  __shared__ int _cnt;                                                         \
  if ((tid) == 0) _cnt = 0;                                                    \
  __syncthreads();                                                             \
  {                                                                            \
    const unsigned char* _mb = (const unsigned char*)(mask);                   \
    int _c = 0;                                                                \
    _Pragma("unroll")                                                          \
    for (int _i = 0; _i < 16; ++_i) _c += (_mb[(tid) * 16 + _i] != 0) ? 1 : 0; \
    atomicAdd(&_cnt, _c);                                                      \
  }                                                                            \
  __syncthreads();                                                             \
  const bool outvar = (_cnt > 2048);

static __device__ __forceinline__ float mask_w(const void* mask, bool bytemode, int e) {
  if (bytemode) return (((const unsigned char*)mask)[e] != 0) ? 1.f : 0.f;
  return (((const int*)mask)[e] != 0) ? 1.f : 0.f;
}

// ---------------- K1: build basis tables + f=4095 replica prep + tau/scal + dm
// blocks [0,4096): basis build; [4096,4100): per-b f32-replica (delta, invA);
// [4100,6148): tau/scal (m in [1,2048]); [6148,8196): dm even/odd split.
__global__ __launch_bounds__(256) void k_pre(const void* __restrict__ mask,
                                             const float* __restrict__ data,
                                             bf16* __restrict__ AE,
                                             bf16* __restrict__ Be,
                                             bf16* __restrict__ dmE,
                                             float4* __restrict__ scal,
                                             float* __restrict__ delta,
                                             float* __restrict__ invA) {
  int bid = blockIdx.x, tid = threadIdx.x;
  if (bid < 4096) {
    // ---- basis build (rotation recurrence: 2 trans + 7 rotations) ----
    int region = bid >> 10;
    int idx = (bid & 1023) * 256 + tid;
    short4v lo, hi;
    if (region < 2) {
      // AE/AO: [4096][512], row r: m=(r&2047)+1, sin if r<2048; tau=2(j+1) / 2j+1
      int r = idx >> 6, j8 = (idx & 63) << 3;
      int m = (r & 2047) + 1;
      bool is_sin = (r < 2048);
      int ph0 = (region == 0) ? ((m * (2 * j8 + 2)) & 8191) : ((m * (2 * j8 + 1)) & 8191);
      int step = (2 * m) & 8191;
      float s = __sinf(ph0 * C_2PI_8192), c = __cosf(ph0 * C_2PI_8192);
      float sr = __sinf(step * C_2PI_8192), cr = __cosf(step * C_2PI_8192);
#pragma unroll
      for (int j = 0; j < 8; ++j) {
        float v = is_sin ? s : c;
        if (j < 4) lo[j] = bf16bits(v); else hi[j - 4] = bf16bits(v);
        float ns = s * cr + c * sr;
        c = c * cr - s * sr;
        s = ns;
      }
      short* dst = (short*)AE + (size_t)region * 2097152 + ((size_t)r << 9) + j8;
      *(short4v*)dst = lo;
      *(short4v*)(dst + 4) = hi;
    } else {
      // Be/Bo: [512][4096], row j: tau=2j+2 / 2j+1
      int jr = idx >> 9, k8 = (idx & 511) << 3;
      int tau = (region == 2) ? (2 * jr + 2) : (2 * jr + 1);
      int m0 = (k8 & 2047) + 1;
      bool is_sin = (k8 < 2048);
      int ph0 = (m0 * tau) & 8191;
      float s = __sinf(ph0 * C_2PI_8192), c = __cosf(ph0 * C_2PI_8192);
      float sr = __sinf(tau * C_2PI_8192), cr = __cosf(tau * C_2PI_8192);
#pragma unroll
      for (int j = 0; j < 8; ++j) {
        float v = is_sin ? s : c;
        if (j < 4) lo[j] = bf16bits(v); else hi[j - 4] = bf16bits(v);
        float ns = s * cr + c * sr;
        c = c * cr - s * sr;
        s = ns;
      }
      short* dst = (short*)Be + (size_t)(region - 2) * 2097152 + ((size_t)jr << 12) + k8;
      *(short4v*)dst = lo;
      *(short4v*)(dst + 4) = hi;
    }
    return;
  }
  DETECT_BYTEMODE(mask, tid, bytemode)
  int wid = tid >> 6, lane = tid & 63;
  if (bid < 4100) {
    // ---- f=4095 (m=4096) sin replica: reference f32 arithmetic, accurate sinf/cosf
    int b = bid - 4096;
    int base_b = b << 10;
    const float W = (float)(6.283185307179586 / 8192.0);
    const float ang = W * 4096.0f;
    __shared__ float red[4][2];
    __shared__ float bc2[2];
    float num = 0.f, den = 0.f;
    for (int t = tid; t < 1024; t += 256) {
      float arg = ang * (float)(t + 1);
      float w = mask_w(mask, bytemode, base_b + t);
      num += w * sinf(2.0f * arg);
      den += w * cosf(2.0f * arg);
    }
#pragma unroll
    for (int m = 32; m; m >>= 1) {
      num += __shfl_xor(num, m, 64);
      den += __shfl_xor(den, m, 64);
    }
    if (lane == 0) { red[wid][0] = num; red[wid][1] = den; }
    __syncthreads();
    if (tid == 0) {
      float a0 = red[0][0] + red[1][0] + red[2][0] + red[3][0];
      float a1 = red[0][1] + red[1][1] + red[2][1] + red[3][1];
      float tau = atan2f(a0, a1) / (2.0f * ang);
      bc2[0] = ang * tau;
    }
    __syncthreads();
    float P = bc2[0];
    float dss = 0.f;
    for (int t = tid; t < 1024; t += 256) {
      float arg = ang * (float)(t + 1);
      float d = sinf(arg - P);
      delta[base_b + t] = d;
      float w = mask_w(mask, bytemode, base_b + t);
      dss += w * d * d;
    }
#pragma unroll
    for (int m = 32; m; m >>= 1) dss += __shfl_xor(dss, m, 64);
    if (lane == 0) red[wid][0] = dss;
    __syncthreads();
    if (tid == 0)
      invA[b] = 1.f / (red[0][0] + red[1][0] + red[2][0] + red[3][0]);
  } else if (bid < 6148) {
    // ---- tau/scal for m in [1,2048]: one wave per (b,f) ----
    int gw = (bid - 4100) * 4 + wid;
    int b = gw >> 11, f = gw & 2047;
    int base_b = b << 10;
    float num = 0.f, den = 0.f, nb = 0.f;
    int f2 = 2 * (f + 1);
    {
      int ph0 = (f2 * (lane + 1)) & 8191;
      int st = (f2 << 6) & 8191;
      float s = __sinf(ph0 * C_2PI_8192), c = __cosf(ph0 * C_2PI_8192);
      float sr = __sinf(st * C_2PI_8192), cr = __cosf(st * C_2PI_8192);
#pragma unroll
      for (int i = 0; i < 16; ++i) {
        float w = mask_w(mask, bytemode, base_b + lane + (i << 6));
        num += w * s;
        den += w * c;
        nb += w;
        float ns = s * cr + c * sr;
        c = c * cr - s * sr;
        s = ns;
      }
    }
#pragma unroll
    for (int m = 32; m; m >>= 1) {
      num += __shfl_xor(num, m, 64);
      den += __shfl_xor(den, m, 64);
      nb += __shfl_xor(nb, m, 64);
    }
    if (lane == 0) {
      float th = 0.5f * atan2f(num, den);
      float c = cosf(th), s = sinf(th);
      float WSS = 0.5f * (nb - den);
      float WCC = 0.5f * (nb + den);
      float WSC = 0.5f * num;
      float den_s = c * c * WSS - 2.f * c * s * WSC + s * s * WCC;
      float den_c = c * c * WCC + 2.f * c * s * WSC + s * s * WSS;
      scal[gw] = make_float4(c, s, 1.f / den_s, 1.f / den_c);
    }
  } else {
    // ---- dm even/odd-tau split ----
    int bc = bid - 6148, b = bc >> 9;
    bf16* dmO = dmE + (1 << 20);
    size_t base = (size_t)bc * 1024 + tid * 4;
    float4 d4 = *(const float4*)(data + base);
    const float* d = (const float*)&d4;
    int me = (b << 10) + tid * 4;
    float wd[4];
#pragma unroll
    for (int j = 0; j < 4; ++j) wd[j] = mask_w(mask, bytemode, me + j) * d[j];
    // t even -> tau odd -> dmO[t/2]; t odd -> tau even -> dmE[(t-1)/2]
    short2v dE, dO;
    dO[0] = bf16bits(wd[0]); dE[0] = bf16bits(wd[1]);
    dO[1] = bf16bits(wd[2]); dE[1] = bf16bits(wd[3]);
    *(short2v*)((short*)dmE + (size_t)bc * 512 + tid * 2) = dE;
    *(short2v*)((short*)dmO + (size_t)bc * 512 + tid * 2) = dO;
  }
}

// ---------------- GEMM1 dual (U=even-tau, V=odd-tau) + butterfly-PQ epilogue --
// 512 threads, 8 waves (2M x 4N), per-wave 64x32 output, acc[4][2] x2.
__global__ __launch_bounds__(512, 4) void k_gemm1_pq(const bf16* __restrict__ dmE,
                                                     const bf16* __restrict__ AE,
                                                     const float4* __restrict__ scal,
                                                     bf16* __restrict__ PQe,
                                                     bf16* __restrict__ PQo) {
  __shared__ bf16 As[128 * 64];
  __shared__ bf16 Bs[128 * 64];
  int bid = blockIdx.x;
  int swz = ((bid & 7) << 6) | (bid >> 3);  // 512 blocks, bijective
  int mt = swz & 15, ft = swz >> 4;          // ft in [0,32)
  int m0 = mt << 7, f0 = ft << 6;
  int tid = threadIdx.x, lane = tid & 63, wid = tid >> 6;
  int wm = (wid >> 2) << 6, wn = (wid & 3) << 5;
  int fr = lane & 15, kh = lane >> 4;

  int r0 = tid >> 3;                          // rows 0-63 per GLOAD wave-set
  int scol = ((tid & 7) ^ (r0 & 7)) << 3;
  const bf16* pa0 = dmE + (size_t)(m0 + r0) * 512 + scol;
  const bf16* pb0;
  const bf16* pb1;
  {
    int row0 = r0, row1 = 64 + r0;
    int g0 = ((row0 >> 4) & 1) * 2048 + f0 + (row0 & 15) + ((row0 >> 5) << 4);
    int g1 = ((row1 >> 4) & 1) * 2048 + f0 + (row1 & 15) + ((row1 >> 5) << 4);
    pb0 = AE + (size_t)g0 * 512 + scol;
    pb1 = AE + (size_t)g1 * 512 + scol;
  }
  char* lA = (char*)As + (wid << 10);
  char* lB = (char*)Bs + (wid << 10);

  f32x4 accU[4][2] = {};
  f32x4 accV[4][2] = {};
  int sw = fr & 7;

#define K_BODY(ACC)                                                              \
  for (int kt = 0; kt < 8; ++kt) {                                               \
    GLOAD(pa0, lA);                                                              \
    GLOAD(pa0 + 32768, lA + 8192);                                               \
    GLOAD(pb0, lB);                                                              \
    GLOAD(pb1, lB + 8192);                                                       \
    pa0 += 64; pb0 += 64; pb1 += 64;                                             \
    __syncthreads();                                                             \
    _Pragma("unroll")                                                            \
    for (int s = 0; s < 2; ++s) {                                                \
      bf16x8 a[4];                                                               \
      _Pragma("unroll")                                                          \
      for (int i = 0; i < 4; ++i)                                                \
        a[i] = *(const bf16x8*)&As[(wm + i * 16 + fr) * 64 + ((((s << 2) + kh) ^ sw) << 3)]; \
      _Pragma("unroll")                                                          \
      for (int j = 0; j < 2; ++j) {                                              \
        bf16x8 bb = *(const bf16x8*)&Bs[(wn + j * 16 + fr) * 64 + ((((s << 2) + kh) ^ sw) << 3)]; \
        _Pragma("unroll")                                                        \
        for (int i = 0; i < 4; ++i)                                              \
          ACC[i][j] = __builtin_amdgcn_mfma_f32_16x16x32_bf16(a[i], bb, ACC[i][j], 0, 0, 0); \
      }                                                                          \
    }                                                                            \
    __syncthreads();                                                             \
  }

  K_BODY(accU)
  pa0 += (1 << 20) - 512;                    // dmO = dmE + 1M elems
  pb0 += (2 << 20) - 512;                    // AO = AE + 2M elems
  pb1 += (2 << 20) - 512;
  K_BODY(accV)
#undef K_BODY

  int b = m0 >> 9;
  short* pqe = (short*)PQe;
  short* pqo = (short*)PQo;
  {
    int f = f0 + (wn >> 1) + fr;             // 16 f's per wave
    float4 sc = scal[(b << 11) + f];
    float c = sc.x, s = sc.y, ids = sc.z, idc = sc.w;
    bool self = (f == 2047);                 // m=2048 pairs with itself
#pragma unroll
    for (int i = 0; i < 4; ++i) {
#pragma unroll
      for (int q = 0; q < 4; ++q) {
        int bc = m0 + wm + i * 16 + (kh << 2) + q;
        float US = accU[i][0][q], UC = accU[i][1][q];
        float VS = accV[i][0][q], VC = accV[i][1][q];
        float Gs = US + VS, Gc = UC + VC;      // freq m
        float gs = VS - US, gc = UC - VC;      // freq 4096-m
        float ss = (c * Gs - s * Gc) * ids;
        float cs = (c * Gc + s * Gs) * idc;
        float P = c * ss + s * cs;
        float Q = c * cs - s * ss;
        float ssp = (c * gs + s * gc) * ids;   // partner scal: (c,-s,ids,idc)
        float csp = (c * gc - s * gs) * idc;
        float Pp = self ? 0.f : (c * ssp - s * csp);
        float Qp = self ? 0.f : (c * csp + s * ssp);
        size_t base = (size_t)bc * 4096 + f;
        pqe[base] = bf16bits(P - Pp);
        pqe[base + 2048] = bf16bits(Q + Qp);
        pqo[base] = bf16bits(P + Pp);
        pqo[base + 2048] = bf16bits(Q - Qp);
      }
    }
  }
}

// ---------------- GEMM2 (NT, eo x split-K=4, fp16 partials), 512 threads ------
__global__ __launch_bounds__(512, 4) void k_gemm2(const bf16* __restrict__ PQe,
                                                  const bf16* __restrict__ Be,
                                                  _Float16* __restrict__ Pe) {
  __shared__ bf16 As[128 * 64];
  __shared__ bf16 Bs[128 * 64];
  int bid = blockIdx.x;
  int swz = ((bid & 7) << 6) | (bid >> 3);  // 512 blocks, bijective
  int eo = swz >> 8;
  int slice = (swz >> 6) & 3;
  int tl = swz & 63;
  int mt = tl & 15, nt = tl >> 4;
  int m0 = mt << 7, n0 = nt << 7;
  int tid = threadIdx.x, lane = tid & 63, wid = tid >> 6;
  int wm = (wid >> 2) << 6, wn = (wid & 3) << 5;
  int fr = lane & 15, kh = lane >> 4;

  const bf16* A = PQe + (size_t)eo * (8 << 20);
  const bf16* B = Be + (size_t)eo * (2 << 20);
  _Float16* C = Pe + (size_t)eo * (8 << 20);

  int r0 = tid >> 3;
  int scol = ((tid & 7) ^ (r0 & 7)) << 3;
  const bf16* pa0 = A + (size_t)slice * 1024 + (size_t)(m0 + r0) * 4096 + scol;
  const bf16* pb0 = B + (size_t)slice * 1024 + (size_t)(n0 + r0) * 4096 + scol;
  _Float16* Cp = C + (size_t)slice * 1048576;
  char* lA = (char*)As + (wid << 10);
  char* lB = (char*)Bs + (wid << 10);

  f32x4 acc[4][2] = {};
  int sw = fr & 7;

  for (int kt = 0; kt < 16; ++kt) {
    GLOAD(pa0, lA);
    GLOAD(pa0 + 262144, lA + 8192);
    GLOAD(pb0, lB);
    GLOAD(pb0 + 262144, lB + 8192);
    pa0 += 64; pb0 += 64;
    __syncthreads();
#pragma unroll
    for (int s = 0; s < 2; ++s) {
      bf16x8 a[4];
#pragma unroll
      for (int i = 0; i < 4; ++i)
        a[i] = *(const bf16x8*)&As[(wm + i * 16 + fr) * 64 + ((((s << 2) + kh) ^ sw) << 3)];
#pragma unroll
      for (int j = 0; j < 2; ++j) {
        bf16x8 bb = *(const bf16x8*)&Bs[(wn + j * 16 + fr) * 64 + ((((s << 2) + kh) ^ sw) << 3)];
#pragma unroll
        for (int i = 0; i < 4; ++i)
          acc[i][j] = __builtin_amdgcn_mfma_f32_16x16x32_bf16(a[i], bb, acc[i][j], 0, 0, 0);
      }
    }
    __syncthreads();
  }
#pragma unroll
  for (int i = 0; i < 4; ++i) {
#pragma unroll
    for (int q = 0; q < 4; ++q) {
      size_t row = m0 + wm + i * 16 + (kh << 2) + q;
      _Float16* cp = Cp + row * 512 + n0 + wn + fr;
#pragma unroll
      for (int j = 0; j < 2; ++j) cp[j * 16] = (_Float16)acc[i][j][q];
    }
  }
}

// ---------------- K-tail: merge partials + all per-bc stats + final select ----
__global__ __launch_bounds__(256) void k_tail(const _Float16* __restrict__ Pe,
                                              const _Float16* __restrict__ Po,
                                              const float* __restrict__ data,
                                              const void* __restrict__ mask,
                                              const float* __restrict__ delta,
                                              const float* __restrict__ invA,
                                              float* __restrict__ out) {
  int bc = blockIdx.x, b = bc >> 9, tid = threadIdx.x;
  DETECT_BYTEMODE(mask, tid, bytemode)
  int wid = tid >> 6, lane = tid & 63;
  size_t base = (size_t)bc * 1024 + tid * 4;
  int jj = tid * 2;
  float r[4] = {0.f, 0.f, 0.f, 0.f};
#pragma unroll
  for (int s = 0; s < 4; ++s) {
    halfx2 pe = *(const halfx2*)(Pe + (size_t)s * 1048576 + (size_t)bc * 512 + jj);
    halfx2 po = *(const halfx2*)(Po + (size_t)s * 1048576 + (size_t)bc * 512 + jj);
    r[0] += (float)po[0];  // t even -> tau odd -> Ro
    r[1] += (float)pe[0];  // t odd  -> tau even -> Re
    r[2] += (float)po[1];
    r[3] += (float)pe[1];
  }
  float4 e4 = *(const float4*)(delta + (b << 10) + tid * 4);
  float4 d4 = *(const float4*)(data + base);
  const float* e = (const float*)&e4;
  const float* d = (const float*)&d4;
  float w[4];
  int me = (b << 10) + tid * 4;
#pragma unroll
  for (int j = 0; j < 4; ++j) w[j] = mask_w(mask, bytemode, me + j);
  // pass 1: nb, data stats, f4095/f4096 fixup dots
  float nbv = 0.f, sd = 0.f, sd2 = 0.f, sdd = 0.f, sdc = 0.f;
#pragma unroll
  for (int j = 0; j < 4; ++j) {
    float wd = w[j] * d[j];
    nbv += w[j];
    sd += wd;
    sd2 += wd * d[j];
    sdd += wd * e[j];
    sdc += (j & 1) ? wd : -wd;  // (-1)^(t+1)
  }
#pragma unroll
  for (int m = 32; m; m >>= 1) {
    nbv += __shfl_xor(nbv, m, 64);
    sd += __shfl_xor(sd, m, 64);
    sd2 += __shfl_xor(sd2, m, 64);
    sdd += __shfl_xor(sdd, m, 64);
    sdc += __shfl_xor(sdc, m, 64);
  }
  __shared__ float red[4][5];
  __shared__ float bcast[3];
  if (lane == 0) {
    red[wid][0] = nbv; red[wid][1] = sd; red[wid][2] = sd2;
    red[wid][3] = sdd; red[wid][4] = sdc;
  }
  __syncthreads();
  if (tid == 0) {
    float n = red[0][0] + red[1][0] + red[2][0] + red[3][0];
    float a1 = red[0][1] + red[1][1] + red[2][1] + red[3][1];
    float a2 = red[0][2] + red[1][2] + red[2][2] + red[3][2];
    float a3 = red[0][3] + red[1][3] + red[2][3] + red[3][3];
    float a4 = red[0][4] + red[1][4] + red[2][4] + red[3][4];
    bcast[0] = a3 * invA[b];                 // ss4095
    bcast[1] = a4 / n;                       // cs4096
    float md = a1 / n;
    bcast[2] = (a2 - n * md * md) / (n - 1.f);  // vd
    red[0][0] = n;
  }
  __syncthreads();
  float ssv = bcast[0], csv = bcast[1];
  float sr = 0.f, sr2 = 0.f;
#pragma unroll
  for (int j = 0; j < 4; ++j) {
    r[j] += e[j] * ssv + ((j & 1) ? csv : -csv);  // sin4095 + cos4096 fixups
    float wr = w[j] * r[j];
    sr += wr;
    sr2 += wr * r[j];
  }
#pragma unroll
  for (int m = 32; m; m >>= 1) {
    sr += __shfl_xor(sr, m, 64);
    sr2 += __shfl_xor(sr2, m, 64);
  }
  __shared__ float red2[4][2];
  __shared__ float s_inv;
  if (lane == 0) { red2[wid][0] = sr; red2[wid][1] = sr2; }
  __syncthreads();
  if (tid == 0) {
    float a0 = red2[0][0] + red2[1][0] + red2[2][0] + red2[3][0];
    float a1 = red2[0][1] + red2[1][1] + red2[2][1] + red2[3][1];
    float n = red[0][0];
    float mr = a0 / n, vr = (a1 - n * mr * mr) / (n - 1.f);
    s_inv = sqrtf(bcast[2] / vr);
  }
  __syncthreads();
  float inv = s_inv;
  float4 o;
  ((float*)&o)[0] = (w[0] != 0.f) ? d[0] : r[0] * inv;
  ((float*)&o)[1] = (w[1] != 0.f) ? d[1] : r[1] * inv;
  ((float*)&o)[2] = (w[2] != 0.f) ? d[2] : r[2] * inv;
  ((float*)&o)[3] = (w[3] != 0.f) ? d[3] : r[3] * inv;
  *(float4*)(out + base) = o;
}

extern "C" void kernel_launch(void* const* d_in, const int* in_sizes, int n_in,
                              void* d_out, int out_size, void* d_ws, size_t ws_size,
                              hipStream_t stream) {
  const float* data = (const float*)d_in[0];
  const void* mask = d_in[1];
  float* out = (float*)d_out;
  char* ws = (char*)d_ws;

  float* invA = (float*)(ws + 16640);
  float* delta = (float*)(ws + 50176);       // 16 KB
  float4* scal = (float4*)(ws + 131072);     // 128 KB
  const size_t MB = 1ull << 20;
  bf16* AE = (bf16*)(ws + 1 * MB);           // AE 4MB @1MB, AO 4MB @5MB (contig)
  bf16* Be = (bf16*)(ws + 9 * MB);           // Be 4MB @9MB, Bo 4MB @13MB (contig)
  bf16* dmE = (bf16*)(ws + 17 * MB);         // dmE 2MB @17MB, dmO 2MB @19MB
  bf16* PQe = (bf16*)(ws + 21 * MB);         // 16MB @21MB
  bf16* PQo = (bf16*)(ws + 37 * MB);         // 16MB @37MB (PQe+8M elems)
  _Float16* Pe = (_Float16*)(ws + 53 * MB);  // 8MB used @53MB
  _Float16* Po = (_Float16*)(ws + 69 * MB);  // 8MB used @69MB (Pe+8M elems)

  // K1: build + prep + tau/scal + dm split (mask-mode detect decentralized)
  k_pre<<<8196, 256, 0, stream>>>(mask, data, AE, Be, dmE, scal, delta, invA);
  // GEMM1 dual: U,V (M=2048,N=4096,K=512 each), butterfly+PQ fused epilogue
  k_gemm1_pq<<<512, 512, 0, stream>>>(dmE, AE, scal, PQe, PQo);
  // GEMM2: Re/Ro (M=2048,N=512,K=4096) x2, split-K=4, fp16 partials
  k_gemm2<<<512, 512, 0, stream>>>(PQe, Be, Pe);
  // K-tail: reduce partials + fixups + stats + final select
  k_tail<<<2048, 256, 0, stream>>>(Pe, Po, data, mask, delta, invA, out);
}